// Round 5
// baseline (401.599 us; speedup 1.0000x reference)
//
#include <hip/hip_runtime.h>
#include <hip/hip_bf16.h>

typedef unsigned short bf16_t;
typedef __attribute__((ext_vector_type(8))) short bf16x8;
typedef __attribute__((ext_vector_type(8))) unsigned short u16x8;
typedef __attribute__((ext_vector_type(4))) float f32x4;

#if defined(__has_builtin)
#if __has_builtin(__builtin_amdgcn_global_load_lds)
#define HAS_GLL 1
#endif
#endif

__device__ __forceinline__ float b2f(bf16_t u) {
    return __uint_as_float(((unsigned int)u) << 16);
}
__device__ __forceinline__ bf16_t f2b(float f) {
    unsigned int x = __float_as_uint(f);
    unsigned int r = x + 0x7fffu + ((x >> 16) & 1u);
    return (bf16_t)(r >> 16);
}
// packed 2x f32 -> bf16x2 (RNE, matches f2b)
__device__ __forceinline__ unsigned int pk2(float a, float b) {
    __hip_bfloat162 t = __float22bfloat162_rn(make_float2(a, b));
    return *(unsigned int*)&t;
}
__device__ __forceinline__ float ldf(const void* p, int i, int isf) {
    return isf ? ((const float*)p)[i] : b2f(((const bf16_t*)p)[i]);
}
// 8 consecutive elements -> bf16x8 (handles f32 or bf16 storage)
__device__ __forceinline__ u16x8 ld8(const void* p, size_t off, int isf) {
    u16x8 o;
    if (isf) {
        const float* f = (const float*)p + off;
        #pragma unroll
        for (int j = 0; j < 8; j++) o[j] = f2b(f[j]);
    } else {
        o = *(const u16x8*)((const bf16_t*)p + off);
    }
    return o;
}

__device__ __forceinline__ void stg16(const bf16_t* g, bf16_t* l) {
#ifdef HAS_GLL
    __builtin_amdgcn_global_load_lds(
        (const __attribute__((address_space(1))) unsigned int*)g,
        (__attribute__((address_space(3))) unsigned int*)l,
        16, 0, 0);
#else
    *(uint4*)l = *(const uint4*)g;
#endif
}

// wave-level bf16-vs-fp32 storage detection (lane i inspects word i of x).
__device__ __forceinline__ int detect_isf(const void* xraw) {
    const unsigned int* w = (const unsigned int*)xraw;
    unsigned int u = w[threadIdx.x & 63];
    float a = fabsf(__uint_as_float(u << 16));
    int g = (a >= 0.0009765625f && a <= 16.0f) ? 1 : 0;
    unsigned long long m = __ballot(g);
    return (__builtin_popcountll(m) >= 32) ? 0 : 1;
}

// ---- params block offsets (floats) ----
#define OFF_S0T0 0
#define OFF_W1   16
#define OFF_S1   592
#define OFF_H1   656
#define OFF_S2   720
#define OFF_H2   784
#define OFF_S3   848
#define OFF_H3   912
#define OFF_S4   976
#define OFF_H4   1040
#define OFF_SC5  1104
#define OFF_H5   1112
#define OFF_SC6  1624
#define OFF_H6   1632
#define OFF_SC7  2144
#define OFF_H7   2152
#define OFF_W8   2280
#define OFF_B8   3304
#define OFF_FLAG 4032

// ---------------------------------------------------------------------------
// ONE setup kernel, 945 blocks, segmented:
//  [0,512)   w5 per-row 64x128 -> 128x64 LDS transpose (coalesced R+W)
//  [512,576) w3 per-oc transpose -> pixel-major
//  [576,640) w4 per-oc transpose -> pixel-major
//  [640,768) w6 copy (u16x8)
//  [768,800) w7 copy (u16x8)
//  [800,944) w2 permute (tiny, gather ok - src L2-resident)
//  944       BN-param fold
// ---------------------------------------------------------------------------
__global__ __launch_bounds__(256) void setup_fold_kernel(
    const void* __restrict__ x,
    const void* __restrict__ w2, const void* __restrict__ w3,
    const void* __restrict__ w4, const void* __restrict__ w5,
    const void* __restrict__ w6, const void* __restrict__ w7,
    bf16_t* __restrict__ w2p, bf16_t* __restrict__ w3p,
    bf16_t* __restrict__ w4p, bf16_t* __restrict__ w5p,
    bf16_t* __restrict__ w6b, bf16_t* __restrict__ w7b,
    const void* __restrict__ bn0p, const void* __restrict__ w1,
    const void* __restrict__ b1, const void* __restrict__ bn1p,
    const void* __restrict__ b2c, const void* __restrict__ bn2p,
    const void* __restrict__ bn3p, const void* __restrict__ bn4p,
    const void* __restrict__ b5, const void* __restrict__ bn5p,
    const void* __restrict__ b6, const void* __restrict__ bn6p,
    const void* __restrict__ b7, const void* __restrict__ bn7p,
    const void* __restrict__ w8, const void* __restrict__ b8,
    float* __restrict__ prm)
{
    const int t  = threadIdx.x;
    const int bb = blockIdx.x;
    const int isf = detect_isf(x);

    if (bb < 512) {
        // w5 row nr: w5p[nr][p*64+c] = w5[nr][c*128+p]
        __shared__ unsigned short ls[128 * 66];
        const int nr = bb;
        const size_t so = (size_t)nr * 8192;
        #pragma unroll
        for (int k = 0; k < 4; k++) {
            const int e0 = (t + k * 256) * 8;      // e = c*128 + p (8 consec p)
            u16x8 v = ld8(w5, so + e0, isf);
            const int c = e0 >> 7, p0 = e0 & 127;
            #pragma unroll
            for (int j = 0; j < 8; j++) ls[(p0 + j) * 66 + c] = v[j];
        }
        __syncthreads();
        #pragma unroll
        for (int k = 0; k < 4; k++) {
            const int d0 = (t + k * 256) * 8;      // d = p*64 + c
            const int p = d0 >> 6, c0 = d0 & 63;
            u16x8 o;
            #pragma unroll
            for (int j = 0; j < 8; j++) o[j] = ls[p * 66 + c0 + j];
            *(u16x8*)(w5p + so + d0) = o;
        }
        return;
    }
    if (bb < 640) {
        // w3/w4 oc: dst[p*4096 + oc*64 + ic] = src[oc*8192 + ic*128 + p]
        __shared__ unsigned short ls[128 * 66];
        const int oc = (bb - 512) & 63;
        const void* src = (bb < 576) ? w3 : w4;
        bf16_t*    dst = (bb < 576) ? w3p : w4p;
        const size_t so = (size_t)oc * 8192;
        #pragma unroll
        for (int k = 0; k < 4; k++) {
            const int e0 = (t + k * 256) * 8;      // e = ic*128 + p
            u16x8 v = ld8(src, so + e0, isf);
            const int ic = e0 >> 7, p0 = e0 & 127;
            #pragma unroll
            for (int j = 0; j < 8; j++) ls[(p0 + j) * 66 + ic] = v[j];
        }
        __syncthreads();
        #pragma unroll
        for (int k = 0; k < 4; k++) {
            const int d0 = (t + k * 256) * 8;      // d = p*64 + ic
            const int p = d0 >> 6, ic0 = d0 & 63;
            u16x8 o;
            #pragma unroll
            for (int j = 0; j < 8; j++) o[j] = ls[p * 66 + ic0 + j];
            *(u16x8*)(dst + (size_t)p * 4096 + oc * 64 + ic0) = o;
        }
        return;
    }
    if (bb < 768) {      // w6: 262144 elems, 8/thread
        const int i0 = ((bb - 640) * 256 + t) * 8;
        *(u16x8*)(w6b + i0) = ld8(w6, i0, isf);
        return;
    }
    if (bb < 800) {      // w7: 65536 elems
        const int i0 = ((bb - 768) * 256 + t) * 8;
        *(u16x8*)(w7b + i0) = ld8(w7, i0, isf);
        return;
    }
    if (bb < 944) {      // w2 permute: 36864 elems (src tiny -> L2 gather ok)
        const int i = (bb - 800) * 256 + t;
        int oc = i / 576, r = i - oc * 576;
        int tap = r >> 6, ic = r & 63;
        w2p[i] = f2b(ldf(w2, oc * 576 + ic * 9 + tap, isf));
        return;
    }

    // ---- fold block (bb == 944) ----
    if (t == 0) prm[OFF_FLAG] = isf ? 1.0f : 0.0f;

    if (t == 0) {
        float g = ldf(bn0p, 0, isf), be = ldf(bn0p, 1, isf);
        float m = ldf(bn0p, 2, isf), v = ldf(bn0p, 3, isf);
        float s = g * rsqrtf(v + 1e-5f);
        prm[OFF_S0T0] = s; prm[OFF_S0T0 + 1] = be - m * s;
    }
    for (int i = t; i < 576; i += 256) prm[OFF_W1 + i] = ldf(w1, i, isf);

    if (t < 64) {
        {
            float g = ldf(bn1p, t, isf), be = ldf(bn1p, 64 + t, isf);
            float m = ldf(bn1p, 128 + t, isf), v = ldf(bn1p, 192 + t, isf);
            float s = g * rsqrtf(v + 1e-5f);
            prm[OFF_S1 + t] = s;
            prm[OFF_H1 + t] = s * ldf(b1, t, isf) + (be - m * s);
        }
        {
            float g = ldf(bn2p, t, isf), be = ldf(bn2p, 64 + t, isf);
            float m = ldf(bn2p, 128 + t, isf), v = ldf(bn2p, 192 + t, isf);
            float s = g * rsqrtf(v + 1e-5f);
            prm[OFF_S2 + t] = s;
            prm[OFF_H2 + t] = s * ldf(b2c, t, isf) + (be - m * s);
        }
        {
            float g = ldf(bn3p, t, isf), be = ldf(bn3p, 64 + t, isf);
            float m = ldf(bn3p, 128 + t, isf), v = ldf(bn3p, 192 + t, isf);
            float s = g * rsqrtf(v + 1e-5f);
            prm[OFF_S3 + t] = s;
            prm[OFF_H3 + t] = be - m * s;
        }
        {
            float g = ldf(bn4p, t, isf), be = ldf(bn4p, 64 + t, isf);
            float m = ldf(bn4p, 128 + t, isf), v = ldf(bn4p, 192 + t, isf);
            float s = g * rsqrtf(v + 1e-5f);
            prm[OFF_S4 + t] = s;
            prm[OFF_H4 + t] = be - m * s;
        }
    }
    {
        float g = ldf(bn5p, 0, isf), be = ldf(bn5p, 1, isf);
        float m = ldf(bn5p, 2, isf), v = ldf(bn5p, 3, isf);
        float s = g * rsqrtf(v + 1e-5f);
        if (t == 0) prm[OFF_SC5] = s;
        for (int i = t; i < 512; i += 256)
            prm[OFF_H5 + i] = s * ldf(b5, i, isf) + (be - m * s);
    }
    {
        float g = ldf(bn6p, 0, isf), be = ldf(bn6p, 1, isf);
        float m = ldf(bn6p, 2, isf), v = ldf(bn6p, 3, isf);
        float s = g * rsqrtf(v + 1e-5f);
        if (t == 0) prm[OFF_SC6] = s;
        for (int i = t; i < 512; i += 256)
            prm[OFF_H6 + i] = s * ldf(b6, i, isf) + (be - m * s);
    }
    {
        float g = ldf(bn7p, 0, isf), be = ldf(bn7p, 1, isf);
        float m = ldf(bn7p, 2, isf), v = ldf(bn7p, 3, isf);
        float s = g * rsqrtf(v + 1e-5f);
        if (t == 0) prm[OFF_SC7] = s;
        if (t < 128) prm[OFF_H7 + t] = s * ldf(b7, t, isf) + (be - m * s);
    }
    for (int i = t; i < 1024; i += 256) prm[OFF_W8 + i] = ldf(w8, i, isf);
    if (t < 8) prm[OFF_B8 + t] = ldf(b8, t, isf);
}

// ---------------------------------------------------------------------------
// conv1: transpose+bn0 -> conv1+bn1+relu.  FOUR samples per block, one
// barrier.  Output PIXEL-MAJOR: c1[p][b][ic], bf16.
// WRITE-COALESCED mapping: oc_grp = t&7, pg = t>>3 -- a wave's 64 lanes
// cover 8 pixels x all 8 oc-groups, so each store step emits 8 FULL 128B
// transactions (old mapping: lane->pixel, 1 MB apart -> 64 x 128B lines
// carrying 16B each = 8x write amplification on the 134 MB c1 store).
// xs reads become 8-lane broadcasts; w1s reads 2-way bank (free).
// ---------------------------------------------------------------------------
__global__ __launch_bounds__(256) void conv1_kernel(
    const void* __restrict__ x, const float* __restrict__ prm,
    bf16_t* __restrict__ c1, int Bc, int c0)
{
    __shared__ float xn[720];          // 4 samples x 180 (10x18 halo image)
    __shared__ float w1s[576];

    const int t = threadIdx.x;
    const int b0 = blockIdx.x * 4;
    const int isf = prm[OFF_FLAG] > 0.5f;
    const float s0 = prm[OFF_S0T0], t0 = prm[OFF_S0T0 + 1];

    for (int i = t; i < 576; i += 256) w1s[i] = prm[OFF_W1 + i];
    for (int i = t; i < 720; i += 256) {
        int s = i / 180, r = i - s * 180;
        int row = r / 18, col = r - row * 18;
        float v = 0.f;
        if (row >= 1 && row <= 8 && col >= 1 && col <= 16)
            v = s0 * ldf(x, (c0 + b0 + s) * 128 + (col - 1) * 8 + (row - 1), isf) + t0;
        xn[i] = v;
    }

    const int oc0 = (t & 7) * 8;       // oc group INNER (coalesced writes)
    const int pg  = t >> 3;            // pixel group OUTER (0..31)

    float s1[8], h1[8];
    #pragma unroll
    for (int j = 0; j < 8; j++) {
        s1[j] = prm[OFF_S1 + oc0 + j];
        h1[j] = prm[OFF_H1 + oc0 + j];
    }
    __syncthreads();

    for (int s = 0; s < 4; s++) {
        const int b = b0 + s;
        const float* xs = xn + s * 180;
        #pragma unroll
        for (int m = 0; m < 4; m++) {
            int p = pg + 32 * m;
            int h = p >> 4, w = p & 15;
            float r[9];
            #pragma unroll
            for (int dh = 0; dh < 3; dh++)
                #pragma unroll
                for (int dw = 0; dw < 3; dw++)
                    r[dh * 3 + dw] = xs[(h + dh) * 18 + (w + dw)];
            u16x8 o;
            #pragma unroll
            for (int j = 0; j < 8; j++) {
                float acc = 0.f;
                #pragma unroll
                for (int k = 0; k < 9; k++) acc += r[k] * w1s[(oc0 + j) * 9 + k];
                o[j] = f2b(fmaxf(s1[j] * acc + h1[j], 0.f));
            }
            *(u16x8*)(c1 + (size_t)p * Bc * 64 + (size_t)b * 64 + oc0) = o;
        }
    }
}

// ---------------------------------------------------------------------------
// Fused MFMA: conv2(im2col K=576) + bn2relu -> lc3(K=64) + bn3relu
//             -> lc4(K=64) + bn4relu.  Grid (Bc/256, 128 pixels).
// R1-measured form (~79 us one-pass, ~1080 TF effective = 43% peak): gll+LDS
// dbuf conv2 pipeline — staging hides L2 LATENCY (not bandwidth); R2's
// direct-from-L2 variant was latency-bound at 2x the time.  XCD swizzle
// keeps each XCD's c1 slab (4 MB) in its own L2.  Do not touch.
// ---------------------------------------------------------------------------
__global__ __launch_bounds__(256) void fused_mfma_kernel(
    const bf16_t* __restrict__ c1, const bf16_t* __restrict__ w2p,
    const bf16_t* __restrict__ w3p, const bf16_t* __restrict__ w4p,
    const float* __restrict__ prm, bf16_t* __restrict__ bufA, int Bc)
{
    __shared__ bf16_t sm[20480];       // exactly 40 KiB
    const int t    = threadIdx.x;
    const int lane = t & 63;
    const int wv   = t >> 6;

    int btile, p;
    {
        const int nbx = gridDim.x;
        const int id = blockIdx.x + nbx * blockIdx.y;
        if ((nbx & 7) == 0) {
            const int xcd = id & 7;
            const int k   = id >> 3;
            p     = k & 127;
            btile = xcd + 8 * (k >> 7);       // one btile per XCD at a time
        } else {
            btile = blockIdx.x; p = blockIdx.y;
        }
    }
    const int m0 = btile * 256;
    const int h  = p >> 4, w = p & 15;

    const int fr = lane & 15;
    const int fg = lane >> 4;
    const int swz4 = (fr >> 1) & 3;

    // hoisted staging coords
    const int gS    = (t & 3) ^ ((t >> 3) & 3);
    const int rA    = t >> 2;
    const int coff0 = rA * 64 + gS * 8;
    const int w2off = rA * 576 + gS * 8;

    // lc3/lc4 weights -> registers now; consumed via ds_write much later
    u16x8 wr3[2], wr4[2];
    {
        const bf16_t* w3b = w3p + (size_t)p * 4096 + coff0;
        const bf16_t* w4b = w4p + (size_t)p * 4096 + coff0;
        wr3[0] = *(const u16x8*)(w3b);
        wr3[1] = *(const u16x8*)(w3b + 32);
        wr4[0] = *(const u16x8*)(w4b);
        wr4[1] = *(const u16x8*)(w4b + 32);
    }

    // acc[i][j]: i = oc tile (M), j = batch tile (N) within wave's 64-row band
    f32x4 acc[4][4];
    #pragma unroll
    for (int i = 0; i < 4; i++)
        #pragma unroll
        for (int j = 0; j < 4; j++)
            acc[i][j] = (f32x4){0.f, 0.f, 0.f, 0.f};

    const bf16_t* c1b = c1 + (size_t)m0 * 64 + coff0;
    const size_t planeStride = (size_t)Bc * 64;

    // ---------------- conv2: fully unrolled dbuf pipeline, 18 k-steps ----------------
    {   // prologue: stage step 0 (tap 0 = (-1,-1)) if valid
        if (h > 0 && w > 0) {
            const bf16_t* ab = c1b + (size_t)((h - 1) * 16 + (w - 1)) * planeStride;
            #pragma unroll
            for (int u = 0; u < 4; u++)
                stg16(ab + u * 4096, sm + t * 8 + u * 2048);
            stg16(w2p + w2off, sm + 16384 + t * 8);
        }
    }
    #pragma unroll
    for (int s = 0; s < 18; s++) {
        const int cur = s & 1;
        __syncthreads();
        if (s + 1 < 18) {
            const int s1  = s + 1;
            const int tap = s1 >> 1;
            const int dh = tap / 3 - 1, dw = tap % 3 - 1;   // compile-time
            const int hh = h + dh, ww = w + dw;
            if (hh >= 0 && hh < 8 && ww >= 0 && ww < 16) {  // uniform
                const int nb  = cur ^ 1;
                const int ic0 = (s1 & 1) * 32;
                const bf16_t* ab = c1b + (size_t)(hh * 16 + ww) * planeStride + ic0;
                #pragma unroll
                for (int u = 0; u < 4; u++)
                    stg16(ab + u * 4096, sm + nb * 8192 + t * 8 + u * 2048);
                stg16(w2p + w2off + tap * 64 + ic0, sm + 16384 + nb * 2048 + t * 8);
            }
        }
        {
            const int tap = s >> 1;
            const int dh = tap / 3 - 1, dw = tap % 3 - 1;   // compile-time
            const int hh = h + dh, ww = w + dw;
            if (hh >= 0 && hh < 8 && ww >= 0 && ww < 16) {  // uniform
                const bf16_t* Ab = sm + cur * 8192;            // activations
                const bf16_t* Bb = sm + 16384 + cur * 2048;    // weights
                bf16x8 hf[4], wf[4];
                #pragma unroll
                for (int j = 0; j < 4; j++)
                    hf[j] = *(const bf16x8*)(Ab + ((wv * 64 + j * 16 + fr) * 4 + (fg ^ swz4)) * 8);
                #pragma unroll
                for (int i = 0; i < 4; i++)
                    wf[i] = *(const bf16x8*)(Bb + ((i * 16 + fr) * 4 + (fg ^ swz4)) * 8);
                #pragma unroll
                for (int i = 0; i < 4; i++)
                    #pragma unroll
                    for (int j = 0; j < 4; j++)
                        acc[i][j] = __builtin_amdgcn_mfma_f32_16x16x32_bf16(
                            wf[i], hf[j], acc[i][j], 0, 0, 0);
            }
        }
    }
    __syncthreads();   // all conv2 LDS reads done (incl. Bs buf1 = lc wt region)

    // epilogue macro: D(m=oc contiguous 4, n=b) -> smC[b][oc], packed b64 writes
#define EPILOGUE(SOFF, HOFF)                                                  \
    _Pragma("unroll")                                                         \
    for (int i = 0; i < 4; i++) {                                             \
        const int oc0e = i * 16 + fg * 4;                                     \
        const float4 sv = *(const float4*)(prm + (SOFF) + oc0e);              \
        const float4 hv = *(const float4*)(prm + (HOFF) + oc0e);              \
        _Pragma("unroll")                                                     \
        for (int j = 0; j < 4; j++) {                                         \
            const int bi = wv * 64 + j * 16 + fr;                             \
            float v0 = fmaxf(sv.x * acc[i][j][0] + hv.x, 0.f);                \
            float v1 = fmaxf(sv.y * acc[i][j][1] + hv.y, 0.f);                \
            float v2 = fmaxf(sv.z * acc[i][j][2] + hv.z, 0.f);                \
            float v3 = fmaxf(sv.w * acc[i][j][3] + hv.w, 0.f);                \
            uint2 pk; pk.x = pk2(v0, v1); pk.y = pk2(v2, v3);                 \
            *(uint2*)(sm + bi * 72 + oc0e) = pk;                              \
        }                                                                     \
    }

    // conv2 epilogue -> smC [b][oc] stride 72 (own band) + stage lc3 ks0 wts
    EPILOGUE(OFF_S2, OFF_H2)
    *(u16x8*)(sm + 18432 + t * 8) = wr3[0];
    __syncthreads();

    // ---------------- lc3: K=64 (weights from registers) ----------------
    #pragma unroll
    for (int i = 0; i < 4; i++)
        #pragma unroll
        for (int j = 0; j < 4; j++)
            acc[i][j] = (f32x4){0.f, 0.f, 0.f, 0.f};

    #pragma unroll
    for (int ks = 0; ks < 2; ks++) {
        if (ks == 1) {
            __syncthreads();                       // all ks0 weight reads done
            *(u16x8*)(sm + 18432 + t * 8) = wr3[1];
            __syncthreads();
        }
        bf16x8 hf[4], wf[4];
        #pragma unroll
        for (int j = 0; j < 4; j++)
            hf[j] = *(const bf16x8*)(sm + (wv * 64 + j * 16 + fr) * 72 + ks * 32 + fg * 8);
        #pragma unroll
        for (int i = 0; i < 4; i++)
            wf[i] = *(const bf16x8*)(sm + 18432 + ((i * 16 + fr) * 4 + (fg ^ swz4)) * 8);
        #pragma unroll
        for (int i = 0; i < 4; i++)
            #pragma unroll
            for (int j = 0; j < 4; j++)
                acc[i][j] = __builtin_amdgcn_mfma_f32_16x16x32_bf16(
                    wf[i], hf[j], acc[i][j], 0, 0, 0);
    }

    // lc3 epilogue (own band; own-band reads already consumed)
    EPILOGUE(OFF_S3, OFF_H3)
    __syncthreads();                               // lc3 ks1 weight reads done
    *(u16x8*)(sm + 18432 + t * 8) = wr4[0];
    __syncthreads();

    // ---------------- lc4: K=64 ----------------
    #pragma unroll
    for (int i = 0; i < 4; i++)
        #pragma unroll
        for (int j = 0; j < 4; j++)
            acc[i][j] = (f32x4){0.f, 0.f, 0.f, 0.f};

    #pragma unroll
    for (int ks = 0; ks < 2; ks++) {
        if (ks == 1) {
            __syncthreads();
            *(u16x8*)(sm + 18432 + t * 8) = wr4[1];
            __syncthreads();
        }
        bf16x8 hf[4], wf[4];
        #pragma unroll
        for (int j = 0; j < 4; j++)
            hf[j] = *(const bf16x8*)(sm + (wv * 64 + j * 16 + fr) * 72 + ks * 32 + fg * 8);
        #pragma unroll
        for (int i = 0; i < 4; i++)
            wf[i] = *(const bf16x8*)(sm + 18432 + ((i * 16 + fr) * 4 + (fg ^ swz4)) * 8);
        #pragma unroll
        for (int i = 0; i < 4; i++)
            #pragma unroll
            for (int j = 0; j < 4; j++)
                acc[i][j] = __builtin_amdgcn_mfma_f32_16x16x32_bf16(
                    wf[i], hf[j], acc[i][j], 0, 0, 0);
    }

    // lc4 epilogue -> smC, then barrier, then coalesced bufA write (all bands)
    EPILOGUE(OFF_S4, OFF_H4)
#undef EPILOGUE
    __syncthreads();

    const int orow = t >> 3, wc0 = (t & 7) * 8;
    #pragma unroll
    for (int pass = 0; pass < 8; pass++) {
        const int row = orow + pass * 32;
        *(uint4*)(bufA + (size_t)(m0 + row) * 8192 + p * 64 + wc0) =
            *(const uint4*)(sm + row * 72 + wc0);
    }
}

// ---------------------------------------------------------------------------
// MFMA GEMM: out[M][N] = relu(s*(A.W^T)+shift), bf16.
// BM=128, BN=64, BK=64.  4 waves 2x2, wave tile 64x32, 16 MFMA per barrier.
// (R1/R4-measured 79 us fc5 = 870 TF, m97-plateau for this shape.  BN=128
// regressed: grid fell to 1 block/CU -> no co-resident block hides the
// per-step vmcnt(0)+barrier drain.)
// XCD swizzle groups an A-panel's N-blocks time-adjacent on one XCD.
// ---------------------------------------------------------------------------
__global__ __launch_bounds__(256) void gemm_mfma(
    const bf16_t* __restrict__ A, const bf16_t* __restrict__ W,
    const float* __restrict__ prm, int sc_off, int sh_off,
    bf16_t* __restrict__ out, int K, int N)
{
    __shared__ bf16_t sm[24576];
    const int t    = threadIdx.x;
    const int lane = t & 63;
    const int wv   = t >> 6;
    const int wr   = wv >> 1, wc = wv & 1;

    int bm, bn;
    {
        const int nx = gridDim.x, ny = gridDim.y;
        const int id = blockIdx.x + nx * blockIdx.y;
        if ((nx & 7) == 0) {
            const int xcd = id & 7;
            const int k   = id >> 3;
            const int pl  = k / ny;       // panel group within this XCD
            bn = k - pl * ny;
            bm = xcd + 8 * pl;
        } else {
            bm = blockIdx.x; bn = blockIdx.y;
        }
    }
    const int m0 = bm * 128, n0 = bn * 64;

    const int fr = lane & 15;
    const int fg = lane >> 4;
    const int swz8 = fr & 7;

    const bf16_t* srcA[4]; bf16_t* dstA[4];
    #pragma unroll
    for (int u = 0; u < 4; u++) {
        const int c = t + 256 * u;
        const int row = c >> 3;
        const int g = (c & 7) ^ (row & 7);
        srcA[u] = A + (size_t)(m0 + row) * K + g * 8;
        dstA[u] = sm + c * 8;
    }
    const bf16_t* srcB[2]; bf16_t* dstB[2];
    #pragma unroll
    for (int u = 0; u < 2; u++) {
        const int c = t + 256 * u;
        const int row = c >> 3;
        const int g = (c & 7) ^ (row & 7);
        srcB[u] = W + (size_t)(n0 + row) * K + g * 8;
        dstB[u] = sm + 16384 + c * 8;
    }

    f32x4 acc[4][2];
    #pragma unroll
    for (int i = 0; i < 4; i++)
        #pragma unroll
        for (int j = 0; j < 2; j++)
            acc[i][j] = (f32x4){0.f, 0.f, 0.f, 0.f};

    const int KS = K >> 6;

    #pragma unroll
    for (int u = 0; u < 4; u++) stg16(srcA[u], dstA[u]);
    #pragma unroll
    for (int u = 0; u < 2; u++) stg16(srcB[u], dstB[u]);

    for (int ks = 0; ks < KS; ks++) {
        const int cur = ks & 1;
        __syncthreads();
        if (ks + 1 < KS) {
            const int nb = cur ^ 1;
            const int kk = (ks + 1) << 6;
            #pragma unroll
            for (int u = 0; u < 4; u++) stg16(srcA[u] + kk, dstA[u] + nb * 8192);
            #pragma unroll
            for (int u = 0; u < 2; u++) stg16(srcB[u] + kk, dstB[u] + nb * 4096);
        }
        const bf16_t* Ab = sm + cur * 8192;
        const bf16_t* Bb = sm + 16384 + cur * 4096;
        bf16x8 af[4][2], bf2[2][2];
        #pragma unroll
        for (int i = 0; i < 4; i++)
            #pragma unroll
            for (int hh = 0; hh < 2; hh++) {
                const int r = wr * 64 + i * 16 + fr;
                const int g = hh * 4 + fg;
                af[i][hh] = *(const bf16x8*)(Ab + (r * 8 + (g ^ swz8)) * 8);
            }
        #pragma unroll
        for (int j = 0; j < 2; j++)
            #pragma unroll
            for (int hh = 0; hh < 2; hh++) {
                const int r = wc * 32 + j * 16 + fr;
                const int g = hh * 4 + fg;
                bf2[j][hh] = *(const bf16x8*)(Bb + (r * 8 + (g ^ swz8)) * 8);
            }
        #pragma unroll
        for (int hh = 0; hh < 2; hh++)
            #pragma unroll
            for (int i = 0; i < 4; i++)
                #pragma unroll
                for (int j = 0; j < 2; j++)
                    acc[i][j] = __builtin_amdgcn_mfma_f32_16x16x32_bf16(
                        af[i][hh], bf2[j][hh], acc[i][j], 0, 0, 0);
    }

    const float s    = prm[sc_off];
    const int   orow = fg * 4;
    const int   ocol = fr;
    #pragma unroll
    for (int j = 0; j < 2; j++) {
        const int n  = n0 + wc * 32 + j * 16 + ocol;
        const float sh = prm[sh_off + n];
        #pragma unroll
        for (int i = 0; i < 4; i++) {
            const int mb = m0 + wr * 64 + i * 16 + orow;
            #pragma unroll
            for (int r = 0; r < 4; r++) {
                float v = fmaxf(s * acc[i][j][r] + sh, 0.f);
                out[(size_t)(mb + r) * N + n] = f2b(v);
            }
        }
    }
}

// ---------------------------------------------------------------------------
// fc8: out[b][n] = h[b][:] . w8[n][:] + b8[n]   (N=8, K=128), h is bf16.
// ---------------------------------------------------------------------------
__global__ __launch_bounds__(256) void fc8_kernel(
    const bf16_t* __restrict__ h, const float* __restrict__ prm,
    void* __restrict__ out, int c0)
{
    __shared__ float wsm[8 * 129];
    const int t = threadIdx.x;
    for (int i = t; i < 1024; i += 256) {
        int n = i >> 7, k = i & 127;
        wsm[n * 129 + k] = prm[OFF_W8 + i];
    }
    __syncthreads();
    const int isf = prm[OFF_FLAG] > 0.5f;
    const int bl = t >> 3, n = t & 7;
    const int b = c0 + blockIdx.x * 32 + bl;
    const bf16_t* hb = h + (size_t)(blockIdx.x * 32 + bl) * 128;
    float acc = prm[OFF_B8 + n];
    #pragma unroll
    for (int k8 = 0; k8 < 16; k8++) {
        u16x8 hv = *(const u16x8*)(hb + k8 * 8);
        #pragma unroll
        for (int j = 0; j < 8; j++)
            acc += b2f(hv[j]) * wsm[n * 129 + k8 * 8 + j];
    }
    if (isf) ((float*)out)[(size_t)b * 8 + n] = acc;
    else     ((bf16_t*)out)[(size_t)b * 8 + n] = f2b(acc);
}

// ---------------------------------------------------------------------------
extern "C" void kernel_launch(void* const* d_in, const int* in_sizes, int n_in,
                              void* d_out, int out_size, void* d_ws, size_t ws_size,
                              hipStream_t stream)
{
    const void* x    = d_in[0];
    const void* bn0p = d_in[1];
    const void* w1   = d_in[2];
    const void* b1   = d_in[3];
    const void* bn1p = d_in[4];
    const void* w2   = d_in[5];
    const void* b2c  = d_in[6];
    const void* bn2p = d_in[7];
    const void* w3   = d_in[8];
    const void* bn3p = d_in[9];
    const void* w4   = d_in[10];
    const void* bn4p = d_in[11];
    const void* w5   = d_in[12];
    const void* b5   = d_in[13];
    const void* bn5p = d_in[14];
    const void* w6   = d_in[15];
    const void* b6   = d_in[16];
    const void* bn6p = d_in[17];
    const void* w7   = d_in[18];
    const void* b7   = d_in[19];
    const void* bn7p = d_in[20];
    const void* w8   = d_in[21];
    const void* b8   = d_in[22];

    char* base = (char*)d_ws;
    float*  prm = (float*)(base + 0);            //    16384 B
    bf16_t* w2p = (bf16_t*)(base + 16384);       //    73728 B
    bf16_t* w3p = (bf16_t*)(base + 90112);       //  1048576 B
    bf16_t* w4p = (bf16_t*)(base + 1138688);     //  1048576 B
    bf16_t* w5p = (bf16_t*)(base + 2187264);     //  8388608 B
    bf16_t* w6b = (bf16_t*)(base + 10575872);    //   524288 B
    bf16_t* w7b = (bf16_t*)(base + 11100160);    //   131072 B
    char*   acts = base + 11231232;

    const int B = 8192;
    const size_t FIXED = 11231232ull;

    setup_fold_kernel<<<945, 256, 0, stream>>>(
        x, w2, w3, w4, w5, w6, w7, w2p, w3p, w4p, w5p, w6b, w7b,
        bn0p, w1, b1, bn1p, b2c, bn2p, bn3p, bn4p,
        b5, bn5p, b6, bn6p, b7, bn7p, w8, b8, prm);

    // one-pass if c1 fits for the whole batch, else 2-chunk, else tight loop
    const size_t NEED_1PASS = FIXED + (size_t)B * 16384ull + (size_t)B * 18688ull;
    const size_t NEED_2PASS = FIXED + 4096ull * 16384ull + (size_t)B * 18688ull;

    if (ws_size >= NEED_2PASS) {
        const int Bf = (ws_size >= NEED_1PASS) ? 8192 : 4096;

        bf16_t* c1   = (bf16_t*)acts;                    // [128][Bf][64]
        bf16_t* bufA = c1 + (size_t)Bf * 8192;           // [B][8192]
        bf16_t* bufC = bufA + (size_t)B * 8192;          // [B][512]
        bf16_t* bufD = bufC + (size_t)B * 512;           // [B][512]
        bf16_t* bufE = bufD + (size_t)B * 512;           // [B][128]

        for (int c0 = 0; c0 < B; c0 += Bf) {
            conv1_kernel<<<Bf / 4, 256, 0, stream>>>(x, prm, c1, Bf, c0);
            fused_mfma_kernel<<<dim3(Bf / 256, 128), 256, 0, stream>>>(
                c1, w2p, w3p, w4p, prm, bufA + (size_t)c0 * 8192, Bf);
        }
        gemm_mfma<<<dim3(B / 128, 8), 256, 0, stream>>>(
            bufA, w5p, prm, OFF_SC5, OFF_H5, bufC, 8192, 512);
        gemm_mfma<<<dim3(B / 128, 8), 256, 0, stream>>>(
            bufC, w6b, prm, OFF_SC6, OFF_H6, bufD, 512, 512);
        gemm_mfma<<<dim3(B / 128, 2), 256, 0, stream>>>(
            bufD, w7b, prm, OFF_SC7, OFF_H7, bufE, 512, 128);
        fc8_kernel<<<B / 32, 256, 0, stream>>>(bufE, prm, d_out, 0);
    } else {
        size_t avail = (ws_size > FIXED) ? (ws_size - FIXED) : 0;
        int Bc = 8192;
        while (Bc > 256 && (size_t)Bc * 35072ull > avail) Bc >>= 1;

        bf16_t* c1   = (bf16_t*)acts;
        bf16_t* bufA = c1 + (size_t)Bc * 8192;
        bf16_t* bufC = bufA + (size_t)Bc * 8192;
        bf16_t* bufD = bufC + (size_t)Bc * 512;
        bf16_t* bufE = bufD + (size_t)Bc * 512;

        for (int c0 = 0; c0 < B; c0 += Bc) {
            conv1_kernel<<<Bc / 4, 256, 0, stream>>>(x, prm, c1, Bc, c0);
            fused_mfma_kernel<<<dim3(Bc / 256, 128), 256, 0, stream>>>(
                c1, w2p, w3p, w4p, prm, bufA, Bc);
            gemm_mfma<<<dim3(Bc / 128, 8), 256, 0, stream>>>(
                bufA, w5p, prm, OFF_SC5, OFF_H5, bufC, 8192, 512);
            gemm_mfma<<<dim3(Bc / 128, 8), 256, 0, stream>>>(
                bufC, w6b, prm, OFF_SC6, OFF_H6, bufD, 512, 512);
            gemm_mfma<<<dim3(Bc / 128, 2), 256, 0, stream>>>(
                bufD, w7b, prm, OFF_SC7, OFF_H7, bufE, 512, 128);
            fc8_kernel<<<Bc / 32, 256, 0, stream>>>(bufE, prm, d_out, c0);
        }
    }
}

// Round 6
// 389.560 us; speedup vs baseline: 1.0309x; 1.0309x over previous
//
#include <hip/hip_runtime.h>
#include <hip/hip_bf16.h>

typedef unsigned short bf16_t;
typedef __attribute__((ext_vector_type(8))) short bf16x8;
typedef __attribute__((ext_vector_type(8))) unsigned short u16x8;
typedef __attribute__((ext_vector_type(4))) float f32x4;

#if defined(__has_builtin)
#if __has_builtin(__builtin_amdgcn_global_load_lds)
#define HAS_GLL 1
#endif
#endif

__device__ __forceinline__ float b2f(bf16_t u) {
    return __uint_as_float(((unsigned int)u) << 16);
}
__device__ __forceinline__ bf16_t f2b(float f) {
    unsigned int x = __float_as_uint(f);
    unsigned int r = x + 0x7fffu + ((x >> 16) & 1u);
    return (bf16_t)(r >> 16);
}
// packed 2x f32 -> bf16x2 (RNE, matches f2b)
__device__ __forceinline__ unsigned int pk2(float a, float b) {
    __hip_bfloat162 t = __float22bfloat162_rn(make_float2(a, b));
    return *(unsigned int*)&t;
}
__device__ __forceinline__ float ldf(const void* p, int i, int isf) {
    return isf ? ((const float*)p)[i] : b2f(((const bf16_t*)p)[i]);
}
// 8 consecutive elements -> bf16x8 (handles f32 or bf16 storage)
__device__ __forceinline__ u16x8 ld8(const void* p, size_t off, int isf) {
    u16x8 o;
    if (isf) {
        const float* f = (const float*)p + off;
        #pragma unroll
        for (int j = 0; j < 8; j++) o[j] = f2b(f[j]);
    } else {
        o = *(const u16x8*)((const bf16_t*)p + off);
    }
    return o;
}

__device__ __forceinline__ void stg16(const bf16_t* g, bf16_t* l) {
#ifdef HAS_GLL
    __builtin_amdgcn_global_load_lds(
        (const __attribute__((address_space(1))) unsigned int*)g,
        (__attribute__((address_space(3))) unsigned int*)l,
        16, 0, 0);
#else
    *(uint4*)l = *(const uint4*)g;
#endif
}

// wave-level bf16-vs-fp32 storage detection (lane i inspects word i of x).
__device__ __forceinline__ int detect_isf(const void* xraw) {
    const unsigned int* w = (const unsigned int*)xraw;
    unsigned int u = w[threadIdx.x & 63];
    float a = fabsf(__uint_as_float(u << 16));
    int g = (a >= 0.0009765625f && a <= 16.0f) ? 1 : 0;
    unsigned long long m = __ballot(g);
    return (__builtin_popcountll(m) >= 32) ? 0 : 1;
}

// ---- params block offsets (floats) ----
#define OFF_S0T0 0
#define OFF_W1   16
#define OFF_S1   592
#define OFF_H1   656
#define OFF_S2   720
#define OFF_H2   784
#define OFF_S3   848
#define OFF_H3   912
#define OFF_S4   976
#define OFF_H4   1040
#define OFF_SC5  1104
#define OFF_H5   1112
#define OFF_SC6  1624
#define OFF_H6   1632
#define OFF_SC7  2144
#define OFF_H7   2152
#define OFF_W8   2280
#define OFF_B8   3304
#define OFF_FLAG 4032

// ---------------------------------------------------------------------------
// ONE setup kernel, segmented:
//  [0,512)   w5 per-row 64x128 -> 128x64 LDS transpose (coalesced R+W)
//  [512,576) w3 per-oc transpose -> pixel-major
//  [576,640) w4 per-oc transpose -> pixel-major
//  [640,768) w6 copy (u16x8)
//  [768,800) w7 copy (u16x8)
//  [800,944) w2 permute (tiny, gather ok - src L2-resident)
//  944       BN-param fold
//  [945, 945+Bf/4)  conv1 for the FULL batch (one-pass mode only).
//    conv1 folds bn0/bn1 LOCALLY from raw params (no prm dependency), so
//    it can run concurrently with the fold block -> conv1's ~25 us overlap
//    the transposes instead of serializing as a separate dispatch.
// ---------------------------------------------------------------------------
__global__ __launch_bounds__(256) void setup_fold_kernel(
    const void* __restrict__ x,
    const void* __restrict__ w2, const void* __restrict__ w3,
    const void* __restrict__ w4, const void* __restrict__ w5,
    const void* __restrict__ w6, const void* __restrict__ w7,
    bf16_t* __restrict__ w2p, bf16_t* __restrict__ w3p,
    bf16_t* __restrict__ w4p, bf16_t* __restrict__ w5p,
    bf16_t* __restrict__ w6b, bf16_t* __restrict__ w7b,
    const void* __restrict__ bn0p, const void* __restrict__ w1,
    const void* __restrict__ b1, const void* __restrict__ bn1p,
    const void* __restrict__ b2c, const void* __restrict__ bn2p,
    const void* __restrict__ bn3p, const void* __restrict__ bn4p,
    const void* __restrict__ b5, const void* __restrict__ bn5p,
    const void* __restrict__ b6, const void* __restrict__ bn6p,
    const void* __restrict__ b7, const void* __restrict__ bn7p,
    const void* __restrict__ w8, const void* __restrict__ b8,
    float* __restrict__ prm, bf16_t* __restrict__ c1, int Bf)
{
    const int t  = threadIdx.x;
    const int bb = blockIdx.x;
    const int isf = detect_isf(x);

    if (bb >= 945) {
        // ---- conv1 segment: transpose+bn0 -> conv1+bn1+relu, 4 samples ----
        const int b0 = (bb - 945) * 4;
        __shared__ float xn[720];
        __shared__ float w1s[576];

        float s0, t0;
        {
            float g = ldf(bn0p, 0, isf), be = ldf(bn0p, 1, isf);
            float m = ldf(bn0p, 2, isf), v = ldf(bn0p, 3, isf);
            s0 = g * rsqrtf(v + 1e-5f); t0 = be - m * s0;
        }
        for (int i = t; i < 576; i += 256) w1s[i] = ldf(w1, i, isf);
        for (int i = t; i < 720; i += 256) {
            int s = i / 180, r = i - s * 180;
            int row = r / 18, col = r - row * 18;
            float v = 0.f;
            if (row >= 1 && row <= 8 && col >= 1 && col <= 16)
                v = s0 * ldf(x, (b0 + s) * 128 + (col - 1) * 8 + (row - 1), isf) + t0;
            xn[i] = v;
        }

        const int oc0 = (t & 7) * 8;
        const int pg  = t >> 3;

        float s1[8], h1[8];
        #pragma unroll
        for (int j = 0; j < 8; j++) {
            const int ch = oc0 + j;
            float g = ldf(bn1p, ch, isf), be = ldf(bn1p, 64 + ch, isf);
            float m = ldf(bn1p, 128 + ch, isf), v = ldf(bn1p, 192 + ch, isf);
            s1[j] = g * rsqrtf(v + 1e-5f);
            h1[j] = s1[j] * ldf(b1, ch, isf) + (be - m * s1[j]);
        }
        __syncthreads();

        for (int s = 0; s < 4; s++) {
            const int b = b0 + s;
            const float* xs = xn + s * 180;
            #pragma unroll
            for (int m = 0; m < 4; m++) {
                int p = pg + 32 * m;
                int h = p >> 4, w = p & 15;
                float r[9];
                #pragma unroll
                for (int dh = 0; dh < 3; dh++)
                    #pragma unroll
                    for (int dw = 0; dw < 3; dw++)
                        r[dh * 3 + dw] = xs[(h + dh) * 18 + (w + dw)];
                u16x8 o;
                #pragma unroll
                for (int j = 0; j < 8; j++) {
                    float acc = 0.f;
                    #pragma unroll
                    for (int k = 0; k < 9; k++) acc += r[k] * w1s[(oc0 + j) * 9 + k];
                    o[j] = f2b(fmaxf(s1[j] * acc + h1[j], 0.f));
                }
                *(u16x8*)(c1 + (size_t)p * Bf * 64 + (size_t)b * 64 + oc0) = o;
            }
        }
        return;
    }

    if (bb < 512) {
        // w5 row nr: w5p[nr][p*64+c] = w5[nr][c*128+p]
        __shared__ unsigned short ls[128 * 66];
        const int nr = bb;
        const size_t so = (size_t)nr * 8192;
        #pragma unroll
        for (int k = 0; k < 4; k++) {
            const int e0 = (t + k * 256) * 8;      // e = c*128 + p (8 consec p)
            u16x8 v = ld8(w5, so + e0, isf);
            const int c = e0 >> 7, p0 = e0 & 127;
            #pragma unroll
            for (int j = 0; j < 8; j++) ls[(p0 + j) * 66 + c] = v[j];
        }
        __syncthreads();
        #pragma unroll
        for (int k = 0; k < 4; k++) {
            const int d0 = (t + k * 256) * 8;      // d = p*64 + c
            const int p = d0 >> 6, c0 = d0 & 63;
            u16x8 o;
            #pragma unroll
            for (int j = 0; j < 8; j++) o[j] = ls[p * 66 + c0 + j];
            *(u16x8*)(w5p + so + d0) = o;
        }
        return;
    }
    if (bb < 640) {
        // w3/w4 oc: dst[p*4096 + oc*64 + ic] = src[oc*8192 + ic*128 + p]
        __shared__ unsigned short ls[128 * 66];
        const int oc = (bb - 512) & 63;
        const void* src = (bb < 576) ? w3 : w4;
        bf16_t*    dst = (bb < 576) ? w3p : w4p;
        const size_t so = (size_t)oc * 8192;
        #pragma unroll
        for (int k = 0; k < 4; k++) {
            const int e0 = (t + k * 256) * 8;      // e = ic*128 + p
            u16x8 v = ld8(src, so + e0, isf);
            const int ic = e0 >> 7, p0 = e0 & 127;
            #pragma unroll
            for (int j = 0; j < 8; j++) ls[(p0 + j) * 66 + ic] = v[j];
        }
        __syncthreads();
        #pragma unroll
        for (int k = 0; k < 4; k++) {
            const int d0 = (t + k * 256) * 8;      // d = p*64 + ic
            const int p = d0 >> 6, ic0 = d0 & 63;
            u16x8 o;
            #pragma unroll
            for (int j = 0; j < 8; j++) o[j] = ls[p * 66 + ic0 + j];
            *(u16x8*)(dst + (size_t)p * 4096 + oc * 64 + ic0) = o;
        }
        return;
    }
    if (bb < 768) {      // w6: 262144 elems, 8/thread
        const int i0 = ((bb - 640) * 256 + t) * 8;
        *(u16x8*)(w6b + i0) = ld8(w6, i0, isf);
        return;
    }
    if (bb < 800) {      // w7: 65536 elems
        const int i0 = ((bb - 768) * 256 + t) * 8;
        *(u16x8*)(w7b + i0) = ld8(w7, i0, isf);
        return;
    }
    if (bb < 944) {      // w2 permute: 36864 elems (src tiny -> L2 gather ok)
        const int i = (bb - 800) * 256 + t;
        int oc = i / 576, r = i - oc * 576;
        int tap = r >> 6, ic = r & 63;
        w2p[i] = f2b(ldf(w2, oc * 576 + ic * 9 + tap, isf));
        return;
    }

    // ---- fold block (bb == 944) ----
    if (t == 0) prm[OFF_FLAG] = isf ? 1.0f : 0.0f;

    if (t == 0) {
        float g = ldf(bn0p, 0, isf), be = ldf(bn0p, 1, isf);
        float m = ldf(bn0p, 2, isf), v = ldf(bn0p, 3, isf);
        float s = g * rsqrtf(v + 1e-5f);
        prm[OFF_S0T0] = s; prm[OFF_S0T0 + 1] = be - m * s;
    }
    for (int i = t; i < 576; i += 256) prm[OFF_W1 + i] = ldf(w1, i, isf);

    if (t < 64) {
        {
            float g = ldf(bn1p, t, isf), be = ldf(bn1p, 64 + t, isf);
            float m = ldf(bn1p, 128 + t, isf), v = ldf(bn1p, 192 + t, isf);
            float s = g * rsqrtf(v + 1e-5f);
            prm[OFF_S1 + t] = s;
            prm[OFF_H1 + t] = s * ldf(b1, t, isf) + (be - m * s);
        }
        {
            float g = ldf(bn2p, t, isf), be = ldf(bn2p, 64 + t, isf);
            float m = ldf(bn2p, 128 + t, isf), v = ldf(bn2p, 192 + t, isf);
            float s = g * rsqrtf(v + 1e-5f);
            prm[OFF_S2 + t] = s;
            prm[OFF_H2 + t] = s * ldf(b2c, t, isf) + (be - m * s);
        }
        {
            float g = ldf(bn3p, t, isf), be = ldf(bn3p, 64 + t, isf);
            float m = ldf(bn3p, 128 + t, isf), v = ldf(bn3p, 192 + t, isf);
            float s = g * rsqrtf(v + 1e-5f);
            prm[OFF_S3 + t] = s;
            prm[OFF_H3 + t] = be - m * s;
        }
        {
            float g = ldf(bn4p, t, isf), be = ldf(bn4p, 64 + t, isf);
            float m = ldf(bn4p, 128 + t, isf), v = ldf(bn4p, 192 + t, isf);
            float s = g * rsqrtf(v + 1e-5f);
            prm[OFF_S4 + t] = s;
            prm[OFF_H4 + t] = be - m * s;
        }
    }
    {
        float g = ldf(bn5p, 0, isf), be = ldf(bn5p, 1, isf);
        float m = ldf(bn5p, 2, isf), v = ldf(bn5p, 3, isf);
        float s = g * rsqrtf(v + 1e-5f);
        if (t == 0) prm[OFF_SC5] = s;
        for (int i = t; i < 512; i += 256)
            prm[OFF_H5 + i] = s * ldf(b5, i, isf) + (be - m * s);
    }
    {
        float g = ldf(bn6p, 0, isf), be = ldf(bn6p, 1, isf);
        float m = ldf(bn6p, 2, isf), v = ldf(bn6p, 3, isf);
        float s = g * rsqrtf(v + 1e-5f);
        if (t == 0) prm[OFF_SC6] = s;
        for (int i = t; i < 512; i += 256)
            prm[OFF_H6 + i] = s * ldf(b6, i, isf) + (be - m * s);
    }
    {
        float g = ldf(bn7p, 0, isf), be = ldf(bn7p, 1, isf);
        float m = ldf(bn7p, 2, isf), v = ldf(bn7p, 3, isf);
        float s = g * rsqrtf(v + 1e-5f);
        if (t == 0) prm[OFF_SC7] = s;
        if (t < 128) prm[OFF_H7 + t] = s * ldf(b7, t, isf) + (be - m * s);
    }
    for (int i = t; i < 1024; i += 256) prm[OFF_W8 + i] = ldf(w8, i, isf);
    if (t < 8) prm[OFF_B8 + t] = ldf(b8, t, isf);
}

// ---------------------------------------------------------------------------
// conv1 standalone (FALLBACK chunked path only; one-pass runs it inside the
// setup kernel).  Reads folds from prm.
// ---------------------------------------------------------------------------
__global__ __launch_bounds__(256) void conv1_kernel(
    const void* __restrict__ x, const float* __restrict__ prm,
    bf16_t* __restrict__ c1, int Bc, int c0)
{
    __shared__ float xn[720];
    __shared__ float w1s[576];

    const int t = threadIdx.x;
    const int b0 = blockIdx.x * 4;
    const int isf = prm[OFF_FLAG] > 0.5f;
    const float s0 = prm[OFF_S0T0], t0 = prm[OFF_S0T0 + 1];

    for (int i = t; i < 576; i += 256) w1s[i] = prm[OFF_W1 + i];
    for (int i = t; i < 720; i += 256) {
        int s = i / 180, r = i - s * 180;
        int row = r / 18, col = r - row * 18;
        float v = 0.f;
        if (row >= 1 && row <= 8 && col >= 1 && col <= 16)
            v = s0 * ldf(x, (c0 + b0 + s) * 128 + (col - 1) * 8 + (row - 1), isf) + t0;
        xn[i] = v;
    }

    const int oc0 = (t & 7) * 8;
    const int pg  = t >> 3;

    float s1[8], h1[8];
    #pragma unroll
    for (int j = 0; j < 8; j++) {
        s1[j] = prm[OFF_S1 + oc0 + j];
        h1[j] = prm[OFF_H1 + oc0 + j];
    }
    __syncthreads();

    for (int s = 0; s < 4; s++) {
        const int b = b0 + s;
        const float* xs = xn + s * 180;
        #pragma unroll
        for (int m = 0; m < 4; m++) {
            int p = pg + 32 * m;
            int h = p >> 4, w = p & 15;
            float r[9];
            #pragma unroll
            for (int dh = 0; dh < 3; dh++)
                #pragma unroll
                for (int dw = 0; dw < 3; dw++)
                    r[dh * 3 + dw] = xs[(h + dh) * 18 + (w + dw)];
            u16x8 o;
            #pragma unroll
            for (int j = 0; j < 8; j++) {
                float acc = 0.f;
                #pragma unroll
                for (int k = 0; k < 9; k++) acc += r[k] * w1s[(oc0 + j) * 9 + k];
                o[j] = f2b(fmaxf(s1[j] * acc + h1[j], 0.f));
            }
            *(u16x8*)(c1 + (size_t)p * Bc * 64 + (size_t)b * 64 + oc0) = o;
        }
    }
}

// ---------------------------------------------------------------------------
// Fused MFMA: conv2(im2col K=576) + bn2relu -> lc3(K=64) + bn3relu
//             -> lc4(K=64) + bn4relu.  Grid (Bc/256, 128 pixels).
// R1-measured form (~79 us one-pass, ~1080 TF effective = 43% peak): gll+LDS
// dbuf conv2 pipeline — staging hides L2 LATENCY (not bandwidth); R2's
// direct-from-L2 variant was latency-bound at 2x the time.  XCD swizzle
// keeps each XCD's c1 slab (4 MB) in its own L2.  Do not touch.
// ---------------------------------------------------------------------------
__global__ __launch_bounds__(256) void fused_mfma_kernel(
    const bf16_t* __restrict__ c1, const bf16_t* __restrict__ w2p,
    const bf16_t* __restrict__ w3p, const bf16_t* __restrict__ w4p,
    const float* __restrict__ prm, bf16_t* __restrict__ bufA, int Bc)
{
    __shared__ bf16_t sm[20480];       // exactly 40 KiB
    const int t    = threadIdx.x;
    const int lane = t & 63;
    const int wv   = t >> 6;

    int btile, p;
    {
        const int nbx = gridDim.x;
        const int id = blockIdx.x + nbx * blockIdx.y;
        if ((nbx & 7) == 0) {
            const int xcd = id & 7;
            const int k   = id >> 3;
            p     = k & 127;
            btile = xcd + 8 * (k >> 7);       // one btile per XCD at a time
        } else {
            btile = blockIdx.x; p = blockIdx.y;
        }
    }
    const int m0 = btile * 256;
    const int h  = p >> 4, w = p & 15;

    const int fr = lane & 15;
    const int fg = lane >> 4;
    const int swz4 = (fr >> 1) & 3;

    // hoisted staging coords
    const int gS    = (t & 3) ^ ((t >> 3) & 3);
    const int rA    = t >> 2;
    const int coff0 = rA * 64 + gS * 8;
    const int w2off = rA * 576 + gS * 8;

    // lc3/lc4 weights -> registers now; consumed via ds_write much later
    u16x8 wr3[2], wr4[2];
    {
        const bf16_t* w3b = w3p + (size_t)p * 4096 + coff0;
        const bf16_t* w4b = w4p + (size_t)p * 4096 + coff0;
        wr3[0] = *(const u16x8*)(w3b);
        wr3[1] = *(const u16x8*)(w3b + 32);
        wr4[0] = *(const u16x8*)(w4b);
        wr4[1] = *(const u16x8*)(w4b + 32);
    }

    // acc[i][j]: i = oc tile (M), j = batch tile (N) within wave's 64-row band
    f32x4 acc[4][4];
    #pragma unroll
    for (int i = 0; i < 4; i++)
        #pragma unroll
        for (int j = 0; j < 4; j++)
            acc[i][j] = (f32x4){0.f, 0.f, 0.f, 0.f};

    const bf16_t* c1b = c1 + (size_t)m0 * 64 + coff0;
    const size_t planeStride = (size_t)Bc * 64;

    // ---------------- conv2: fully unrolled dbuf pipeline, 18 k-steps ----------------
    {   // prologue: stage step 0 (tap 0 = (-1,-1)) if valid
        if (h > 0 && w > 0) {
            const bf16_t* ab = c1b + (size_t)((h - 1) * 16 + (w - 1)) * planeStride;
            #pragma unroll
            for (int u = 0; u < 4; u++)
                stg16(ab + u * 4096, sm + t * 8 + u * 2048);
            stg16(w2p + w2off, sm + 16384 + t * 8);
        }
    }
    #pragma unroll
    for (int s = 0; s < 18; s++) {
        const int cur = s & 1;
        __syncthreads();
        if (s + 1 < 18) {
            const int s1  = s + 1;
            const int tap = s1 >> 1;
            const int dh = tap / 3 - 1, dw = tap % 3 - 1;   // compile-time
            const int hh = h + dh, ww = w + dw;
            if (hh >= 0 && hh < 8 && ww >= 0 && ww < 16) {  // uniform
                const int nb  = cur ^ 1;
                const int ic0 = (s1 & 1) * 32;
                const bf16_t* ab = c1b + (size_t)(hh * 16 + ww) * planeStride + ic0;
                #pragma unroll
                for (int u = 0; u < 4; u++)
                    stg16(ab + u * 4096, sm + nb * 8192 + t * 8 + u * 2048);
                stg16(w2p + w2off + tap * 64 + ic0, sm + 16384 + nb * 2048 + t * 8);
            }
        }
        {
            const int tap = s >> 1;
            const int dh = tap / 3 - 1, dw = tap % 3 - 1;   // compile-time
            const int hh = h + dh, ww = w + dw;
            if (hh >= 0 && hh < 8 && ww >= 0 && ww < 16) {  // uniform
                const bf16_t* Ab = sm + cur * 8192;            // activations
                const bf16_t* Bb = sm + 16384 + cur * 2048;    // weights
                bf16x8 hf[4], wf[4];
                #pragma unroll
                for (int j = 0; j < 4; j++)
                    hf[j] = *(const bf16x8*)(Ab + ((wv * 64 + j * 16 + fr) * 4 + (fg ^ swz4)) * 8);
                #pragma unroll
                for (int i = 0; i < 4; i++)
                    wf[i] = *(const bf16x8*)(Bb + ((i * 16 + fr) * 4 + (fg ^ swz4)) * 8);
                #pragma unroll
                for (int i = 0; i < 4; i++)
                    #pragma unroll
                    for (int j = 0; j < 4; j++)
                        acc[i][j] = __builtin_amdgcn_mfma_f32_16x16x32_bf16(
                            wf[i], hf[j], acc[i][j], 0, 0, 0);
            }
        }
    }
    __syncthreads();   // all conv2 LDS reads done (incl. Bs buf1 = lc wt region)

    // epilogue macro: D(m=oc contiguous 4, n=b) -> smC[b][oc], packed b64 writes
#define EPILOGUE(SOFF, HOFF)                                                  \
    _Pragma("unroll")                                                         \
    for (int i = 0; i < 4; i++) {                                             \
        const int oc0e = i * 16 + fg * 4;                                     \
        const float4 sv = *(const float4*)(prm + (SOFF) + oc0e);              \
        const float4 hv = *(const float4*)(prm + (HOFF) + oc0e);              \
        _Pragma("unroll")                                                     \
        for (int j = 0; j < 4; j++) {                                         \
            const int bi = wv * 64 + j * 16 + fr;                             \
            float v0 = fmaxf(sv.x * acc[i][j][0] + hv.x, 0.f);                \
            float v1 = fmaxf(sv.y * acc[i][j][1] + hv.y, 0.f);                \
            float v2 = fmaxf(sv.z * acc[i][j][2] + hv.z, 0.f);                \
            float v3 = fmaxf(sv.w * acc[i][j][3] + hv.w, 0.f);                \
            uint2 pk; pk.x = pk2(v0, v1); pk.y = pk2(v2, v3);                 \
            *(uint2*)(sm + bi * 72 + oc0e) = pk;                              \
        }                                                                     \
    }

    // conv2 epilogue -> smC [b][oc] stride 72 (own band) + stage lc3 ks0 wts
    EPILOGUE(OFF_S2, OFF_H2)
    *(u16x8*)(sm + 18432 + t * 8) = wr3[0];
    __syncthreads();

    // ---------------- lc3: K=64 (weights from registers) ----------------
    #pragma unroll
    for (int i = 0; i < 4; i++)
        #pragma unroll
        for (int j = 0; j < 4; j++)
            acc[i][j] = (f32x4){0.f, 0.f, 0.f, 0.f};

    #pragma unroll
    for (int ks = 0; ks < 2; ks++) {
        if (ks == 1) {
            __syncthreads();                       // all ks0 weight reads done
            *(u16x8*)(sm + 18432 + t * 8) = wr3[1];
            __syncthreads();
        }
        bf16x8 hf[4], wf[4];
        #pragma unroll
        for (int j = 0; j < 4; j++)
            hf[j] = *(const bf16x8*)(sm + (wv * 64 + j * 16 + fr) * 72 + ks * 32 + fg * 8);
        #pragma unroll
        for (int i = 0; i < 4; i++)
            wf[i] = *(const bf16x8*)(sm + 18432 + ((i * 16 + fr) * 4 + (fg ^ swz4)) * 8);
        #pragma unroll
        for (int i = 0; i < 4; i++)
            #pragma unroll
            for (int j = 0; j < 4; j++)
                acc[i][j] = __builtin_amdgcn_mfma_f32_16x16x32_bf16(
                    wf[i], hf[j], acc[i][j], 0, 0, 0);
    }

    // lc3 epilogue (own band; own-band reads already consumed)
    EPILOGUE(OFF_S3, OFF_H3)
    __syncthreads();                               // lc3 ks1 weight reads done
    *(u16x8*)(sm + 18432 + t * 8) = wr4[0];
    __syncthreads();

    // ---------------- lc4: K=64 ----------------
    #pragma unroll
    for (int i = 0; i < 4; i++)
        #pragma unroll
        for (int j = 0; j < 4; j++)
            acc[i][j] = (f32x4){0.f, 0.f, 0.f, 0.f};

    #pragma unroll
    for (int ks = 0; ks < 2; ks++) {
        if (ks == 1) {
            __syncthreads();
            *(u16x8*)(sm + 18432 + t * 8) = wr4[1];
            __syncthreads();
        }
        bf16x8 hf[4], wf[4];
        #pragma unroll
        for (int j = 0; j < 4; j++)
            hf[j] = *(const bf16x8*)(sm + (wv * 64 + j * 16 + fr) * 72 + ks * 32 + fg * 8);
        #pragma unroll
        for (int i = 0; i < 4; i++)
            wf[i] = *(const bf16x8*)(sm + 18432 + ((i * 16 + fr) * 4 + (fg ^ swz4)) * 8);
        #pragma unroll
        for (int i = 0; i < 4; i++)
            #pragma unroll
            for (int j = 0; j < 4; j++)
                acc[i][j] = __builtin_amdgcn_mfma_f32_16x16x32_bf16(
                    wf[i], hf[j], acc[i][j], 0, 0, 0);
    }

    // lc4 epilogue -> smC, then barrier, then coalesced bufA write (all bands)
    EPILOGUE(OFF_S4, OFF_H4)
#undef EPILOGUE
    __syncthreads();

    const int orow = t >> 3, wc0 = (t & 7) * 8;
    #pragma unroll
    for (int pass = 0; pass < 8; pass++) {
        const int row = orow + pass * 32;
        *(uint4*)(bufA + (size_t)(m0 + row) * 8192 + p * 64 + wc0) =
            *(const uint4*)(sm + row * 72 + wc0);
    }
}

// ---------------------------------------------------------------------------
// MFMA GEMM: out[M][N] = relu(s*(A.W^T)+shift), bf16.
// BM=128, BN=64, BK=64.  4 waves 2x2, wave tile 64x32, 16 MFMA per barrier.
// (R1/R4-measured ~80 us fc5 = 860-870 TF, m97-plateau for this shape.)
// XCD swizzle groups an A-panel's N-blocks time-adjacent on one XCD.
// ---------------------------------------------------------------------------
__global__ __launch_bounds__(256) void gemm_mfma(
    const bf16_t* __restrict__ A, const bf16_t* __restrict__ W,
    const float* __restrict__ prm, int sc_off, int sh_off,
    bf16_t* __restrict__ out, int K, int N)
{
    __shared__ bf16_t sm[24576];
    const int t    = threadIdx.x;
    const int lane = t & 63;
    const int wv   = t >> 6;
    const int wr   = wv >> 1, wc = wv & 1;

    int bm, bn;
    {
        const int nx = gridDim.x, ny = gridDim.y;
        const int id = blockIdx.x + nx * blockIdx.y;
        if ((nx & 7) == 0) {
            const int xcd = id & 7;
            const int k   = id >> 3;
            const int pl  = k / ny;       // panel group within this XCD
            bn = k - pl * ny;
            bm = xcd + 8 * pl;
        } else {
            bm = blockIdx.x; bn = blockIdx.y;
        }
    }
    const int m0 = bm * 128, n0 = bn * 64;

    const int fr = lane & 15;
    const int fg = lane >> 4;
    const int swz8 = fr & 7;

    const bf16_t* srcA[4]; bf16_t* dstA[4];
    #pragma unroll
    for (int u = 0; u < 4; u++) {
        const int c = t + 256 * u;
        const int row = c >> 3;
        const int g = (c & 7) ^ (row & 7);
        srcA[u] = A + (size_t)(m0 + row) * K + g * 8;
        dstA[u] = sm + c * 8;
    }
    const bf16_t* srcB[2]; bf16_t* dstB[2];
    #pragma unroll
    for (int u = 0; u < 2; u++) {
        const int c = t + 256 * u;
        const int row = c >> 3;
        const int g = (c & 7) ^ (row & 7);
        srcB[u] = W + (size_t)(n0 + row) * K + g * 8;
        dstB[u] = sm + 16384 + c * 8;
    }

    f32x4 acc[4][2];
    #pragma unroll
    for (int i = 0; i < 4; i++)
        #pragma unroll
        for (int j = 0; j < 2; j++)
            acc[i][j] = (f32x4){0.f, 0.f, 0.f, 0.f};

    const int KS = K >> 6;

    #pragma unroll
    for (int u = 0; u < 4; u++) stg16(srcA[u], dstA[u]);
    #pragma unroll
    for (int u = 0; u < 2; u++) stg16(srcB[u], dstB[u]);

    for (int ks = 0; ks < KS; ks++) {
        const int cur = ks & 1;
        __syncthreads();
        if (ks + 1 < KS) {
            const int nb = cur ^ 1;
            const int kk = (ks + 1) << 6;
            #pragma unroll
            for (int u = 0; u < 4; u++) stg16(srcA[u] + kk, dstA[u] + nb * 8192);
            #pragma unroll
            for (int u = 0; u < 2; u++) stg16(srcB[u] + kk, dstB[u] + nb * 4096);
        }
        const bf16_t* Ab = sm + cur * 8192;
        const bf16_t* Bb = sm + 16384 + cur * 4096;
        bf16x8 af[4][2], bf2[2][2];
        #pragma unroll
        for (int i = 0; i < 4; i++)
            #pragma unroll
            for (int hh = 0; hh < 2; hh++) {
                const int r = wr * 64 + i * 16 + fr;
                const int g = hh * 4 + fg;
                af[i][hh] = *(const bf16x8*)(Ab + (r * 8 + (g ^ swz8)) * 8);
            }
        #pragma unroll
        for (int j = 0; j < 2; j++)
            #pragma unroll
            for (int hh = 0; hh < 2; hh++) {
                const int r = wc * 32 + j * 16 + fr;
                const int g = hh * 4 + fg;
                bf2[j][hh] = *(const bf16x8*)(Bb + (r * 8 + (g ^ swz8)) * 8);
            }
        #pragma unroll
        for (int hh = 0; hh < 2; hh++)
            #pragma unroll
            for (int i = 0; i < 4; i++)
                #pragma unroll
                for (int j = 0; j < 2; j++)
                    acc[i][j] = __builtin_amdgcn_mfma_f32_16x16x32_bf16(
                        af[i][hh], bf2[j][hh], acc[i][j], 0, 0, 0);
    }

    const float s    = prm[sc_off];
    const int   orow = fg * 4;
    const int   ocol = fr;
    #pragma unroll
    for (int j = 0; j < 2; j++) {
        const int n  = n0 + wc * 32 + j * 16 + ocol;
        const float sh = prm[sh_off + n];
        #pragma unroll
        for (int i = 0; i < 4; i++) {
            const int mb = m0 + wr * 64 + i * 16 + orow;
            #pragma unroll
            for (int r = 0; r < 4; r++) {
                float v = fmaxf(s * acc[i][j][r] + sh, 0.f);
                out[(size_t)(mb + r) * N + n] = f2b(v);
            }
        }
    }
}

// ---------------------------------------------------------------------------
// fc78: fused fc7 (N=128, K=512, bn7+relu) -> fc8 (128->8) per 128-row block.
// fc7 is the gemm structure with BN=128 (full feature width per block, NJ=4),
// output held in LDS (stride 130 -> conflict-free column reads), then fc8
// computed in-block and written straight to d_out.  Removes one dispatch and
// the bufE HBM round-trip.  Grid (M/128).
// ---------------------------------------------------------------------------
__global__ __launch_bounds__(256) void fc78_kernel(
    const bf16_t* __restrict__ A, const bf16_t* __restrict__ W,
    const float* __restrict__ prm, void* __restrict__ out, int c0)
{
    __shared__ bf16_t sm[32768];       // 64 KB: k-loop staging; then smC+w8s
    const int t    = threadIdx.x;
    const int lane = t & 63;
    const int wv   = t >> 6;
    const int wr   = wv >> 1, wc = wv & 1;
    const int m0   = blockIdx.x * 128;
    const int K    = 512;

    const int fr = lane & 15;
    const int fg = lane >> 4;
    const int swz8 = fr & 7;

    const bf16_t* srcA[4]; bf16_t* dstA[4];
    #pragma unroll
    for (int u = 0; u < 4; u++) {
        const int c = t + 256 * u;
        const int row = c >> 3;
        const int g = (c & 7) ^ (row & 7);
        srcA[u] = A + (size_t)(m0 + row) * K + g * 8;
        dstA[u] = sm + c * 8;
    }
    const bf16_t* srcB[4]; bf16_t* dstB[4];
    #pragma unroll
    for (int u = 0; u < 4; u++) {
        const int c = t + 256 * u;
        const int row = c >> 3;
        const int g = (c & 7) ^ (row & 7);
        srcB[u] = W + (size_t)row * K + g * 8;
        dstB[u] = sm + 16384 + c * 8;
    }

    f32x4 acc[4][4];
    #pragma unroll
    for (int i = 0; i < 4; i++)
        #pragma unroll
        for (int j = 0; j < 4; j++)
            acc[i][j] = (f32x4){0.f, 0.f, 0.f, 0.f};

    const int KS = 8;

    #pragma unroll
    for (int u = 0; u < 4; u++) stg16(srcA[u], dstA[u]);
    #pragma unroll
    for (int u = 0; u < 4; u++) stg16(srcB[u], dstB[u]);

    for (int ks = 0; ks < KS; ks++) {
        const int cur = ks & 1;
        __syncthreads();
        if (ks + 1 < KS) {
            const int nb = cur ^ 1;
            const int kk = (ks + 1) << 6;
            #pragma unroll
            for (int u = 0; u < 4; u++) stg16(srcA[u] + kk, dstA[u] + nb * 8192);
            #pragma unroll
            for (int u = 0; u < 4; u++) stg16(srcB[u] + kk, dstB[u] + nb * 8192);
        }
        const bf16_t* Ab = sm + cur * 8192;
        const bf16_t* Bb = sm + 16384 + cur * 8192;
        bf16x8 af[4][2], bf2[4][2];
        #pragma unroll
        for (int i = 0; i < 4; i++)
            #pragma unroll
            for (int hh = 0; hh < 2; hh++) {
                const int r = wr * 64 + i * 16 + fr;
                const int g = hh * 4 + fg;
                af[i][hh] = *(const bf16x8*)(Ab + (r * 8 + (g ^ swz8)) * 8);
            }
        #pragma unroll
        for (int j = 0; j < 4; j++)
            #pragma unroll
            for (int hh = 0; hh < 2; hh++) {
                const int r = wc * 64 + j * 16 + fr;
                const int g = hh * 4 + fg;
                bf2[j][hh] = *(const bf16x8*)(Bb + (r * 8 + (g ^ swz8)) * 8);
            }
        #pragma unroll
        for (int hh = 0; hh < 2; hh++)
            #pragma unroll
            for (int i = 0; i < 4; i++)
                #pragma unroll
                for (int j = 0; j < 4; j++)
                    acc[i][j] = __builtin_amdgcn_mfma_f32_16x16x32_bf16(
                        af[i][hh], bf2[j][hh], acc[i][j], 0, 0, 0);
    }

    // all k-loop LDS reads done -> reuse sm: smC [128][130] bf16 + w8s f32
    __syncthreads();
    float* w8s = (float*)(sm + 16640);            // bytes 33280..37375
    for (int i = t; i < 1024; i += 256) w8s[i] = prm[OFF_W8 + i];

    const float s = prm[OFF_SC7];
    #pragma unroll
    for (int j = 0; j < 4; j++) {
        const int n  = wc * 64 + j * 16 + fr;
        const float sh = prm[OFF_H7 + n];
        #pragma unroll
        for (int i = 0; i < 4; i++) {
            const int row0 = wr * 64 + i * 16 + fg * 4;
            #pragma unroll
            for (int r = 0; r < 4; r++) {
                float v = fmaxf(s * acc[i][j][r] + sh, 0.f);
                sm[(row0 + r) * 130 + n] = f2b(v);
            }
        }
    }
    __syncthreads();

    // fc8: thread t -> row r = t&127, n-half = t>>7 (4 outputs)
    const int isf = prm[OFF_FLAG] > 0.5f;
    const int r   = t & 127;
    const int n4  = (t >> 7) * 4;
    float a4[4];
    #pragma unroll
    for (int q = 0; q < 4; q++) a4[q] = prm[OFF_B8 + n4 + q];
    for (int k = 0; k < 128; k++) {
        const float hv = b2f(sm[r * 130 + k]);
        #pragma unroll
        for (int q = 0; q < 4; q++) a4[q] += hv * w8s[(n4 + q) * 128 + k];
    }
    const size_t ob = (size_t)(c0 + m0 + r) * 8 + n4;
    if (isf) {
        float4 o4 = make_float4(a4[0], a4[1], a4[2], a4[3]);
        *(float4*)((float*)out + ob) = o4;
    } else {
        uint2 pk; pk.x = pk2(a4[0], a4[1]); pk.y = pk2(a4[2], a4[3]);
        *(uint2*)((bf16_t*)out + ob) = pk;
    }
}

// ---------------------------------------------------------------------------
extern "C" void kernel_launch(void* const* d_in, const int* in_sizes, int n_in,
                              void* d_out, int out_size, void* d_ws, size_t ws_size,
                              hipStream_t stream)
{
    const void* x    = d_in[0];
    const void* bn0p = d_in[1];
    const void* w1   = d_in[2];
    const void* b1   = d_in[3];
    const void* bn1p = d_in[4];
    const void* w2   = d_in[5];
    const void* b2c  = d_in[6];
    const void* bn2p = d_in[7];
    const void* w3   = d_in[8];
    const void* bn3p = d_in[9];
    const void* w4   = d_in[10];
    const void* bn4p = d_in[11];
    const void* w5   = d_in[12];
    const void* b5   = d_in[13];
    const void* bn5p = d_in[14];
    const void* w6   = d_in[15];
    const void* b6   = d_in[16];
    const void* bn6p = d_in[17];
    const void* w7   = d_in[18];
    const void* b7   = d_in[19];
    const void* bn7p = d_in[20];
    const void* w8   = d_in[21];
    const void* b8   = d_in[22];

    char* base = (char*)d_ws;
    float*  prm = (float*)(base + 0);            //    16384 B
    bf16_t* w2p = (bf16_t*)(base + 16384);       //    73728 B
    bf16_t* w3p = (bf16_t*)(base + 90112);       //  1048576 B
    bf16_t* w4p = (bf16_t*)(base + 1138688);     //  1048576 B
    bf16_t* w5p = (bf16_t*)(base + 2187264);     //  8388608 B
    bf16_t* w6b = (bf16_t*)(base + 10575872);    //   524288 B
    bf16_t* w7b = (bf16_t*)(base + 11100160);    //   131072 B
    char*   acts = base + 11231232;

    const int B = 8192;
    const size_t FIXED = 11231232ull;

    // one-pass if c1 fits for the whole batch, else 2-chunk, else tight loop
    const size_t NEED_1PASS = FIXED + (size_t)B * 16384ull + (size_t)B * 18688ull;
    const size_t NEED_2PASS = FIXED + 4096ull * 16384ull + (size_t)B * 18688ull;

    if (ws_size >= NEED_2PASS) {
        const int Bf = (ws_size >= NEED_1PASS) ? 8192 : 4096;

        bf16_t* c1   = (bf16_t*)acts;                    // [128][Bf][64]
        bf16_t* bufA = c1 + (size_t)Bf * 8192;           // [B][8192]
        bf16_t* bufC = bufA + (size_t)B * 8192;          // [B][512]
        bf16_t* bufD = bufC + (size_t)B * 512;           // [B][512]

        // conv1 runs inside setup (overlapped) when one-pass
        const int extra = (Bf == 8192) ? Bf / 4 : 0;
        setup_fold_kernel<<<945 + extra, 256, 0, stream>>>(
            x, w2, w3, w4, w5, w6, w7, w2p, w3p, w4p, w5p, w6b, w7b,
            bn0p, w1, b1, bn1p, b2c, bn2p, bn3p, bn4p,
            b5, bn5p, b6, bn6p, b7, bn7p, w8, b8, prm, c1, Bf);

        for (int c0 = 0; c0 < B; c0 += Bf) {
            if (extra == 0)
                conv1_kernel<<<Bf / 4, 256, 0, stream>>>(x, prm, c1, Bf, c0);
            fused_mfma_kernel<<<dim3(Bf / 256, 128), 256, 0, stream>>>(
                c1, w2p, w3p, w4p, prm, bufA + (size_t)c0 * 8192, Bf);
        }
        gemm_mfma<<<dim3(B / 128, 8), 256, 0, stream>>>(
            bufA, w5p, prm, OFF_SC5, OFF_H5, bufC, 8192, 512);
        gemm_mfma<<<dim3(B / 128, 8), 256, 0, stream>>>(
            bufC, w6b, prm, OFF_SC6, OFF_H6, bufD, 512, 512);
        fc78_kernel<<<B / 128, 256, 0, stream>>>(bufD, w7b, prm, d_out, 0);
    } else {
        size_t avail = (ws_size > FIXED) ? (ws_size - FIXED) : 0;
        int Bc = 8192;
        while (Bc > 256 && (size_t)Bc * 35072ull > avail) Bc >>= 1;

        bf16_t* c1   = (bf16_t*)acts;
        bf16_t* bufA = c1 + (size_t)Bc * 8192;
        bf16_t* bufC = bufA + (size_t)Bc * 8192;
        bf16_t* bufD = bufC + (size_t)Bc * 512;

        setup_fold_kernel<<<945, 256, 0, stream>>>(
            x, w2, w3, w4, w5, w6, w7, w2p, w3p, w4p, w5p, w6b, w7b,
            bn0p, w1, b1, bn1p, b2c, bn2p, bn3p, bn4p,
            b5, bn5p, b6, bn6p, b7, bn7p, w8, b8, prm, c1, Bc);

        for (int c0 = 0; c0 < B; c0 += Bc) {
            conv1_kernel<<<Bc / 4, 256, 0, stream>>>(x, prm, c1, Bc, c0);
            fused_mfma_kernel<<<dim3(Bc / 256, 128), 256, 0, stream>>>(
                c1, w2p, w3p, w4p, prm, bufA, Bc);
            gemm_mfma<<<dim3(Bc / 128, 8), 256, 0, stream>>>(
                bufA, w5p, prm, OFF_SC5, OFF_H5, bufC, 8192, 512);
            gemm_mfma<<<dim3(Bc / 128, 8), 256, 0, stream>>>(
                bufC, w6b, prm, OFF_SC6, OFF_H6, bufD, 512, 512);
            fc78_kernel<<<Bc / 128, 256, 0, stream>>>(bufD, w7b, prm, d_out, c0);
        }
    }
}

// Round 7
// 388.337 us; speedup vs baseline: 1.0342x; 1.0032x over previous
//
#include <hip/hip_runtime.h>
#include <hip/hip_bf16.h>

typedef unsigned short bf16_t;
typedef __attribute__((ext_vector_type(8))) short bf16x8;
typedef __attribute__((ext_vector_type(8))) unsigned short u16x8;
typedef __attribute__((ext_vector_type(4))) float f32x4;

#if defined(__has_builtin)
#if __has_builtin(__builtin_amdgcn_global_load_lds)
#define HAS_GLL 1
#endif
#endif

__device__ __forceinline__ float b2f(bf16_t u) {
    return __uint_as_float(((unsigned int)u) << 16);
}
__device__ __forceinline__ bf16_t f2b(float f) {
    unsigned int x = __float_as_uint(f);
    unsigned int r = x + 0x7fffu + ((x >> 16) & 1u);
    return (bf16_t)(r >> 16);
}
// packed 2x f32 -> bf16x2 (RNE, matches f2b)
__device__ __forceinline__ unsigned int pk2(float a, float b) {
    __hip_bfloat162 t = __float22bfloat162_rn(make_float2(a, b));
    return *(unsigned int*)&t;
}
__device__ __forceinline__ float ldf(const void* p, int i, int isf) {
    return isf ? ((const float*)p)[i] : b2f(((const bf16_t*)p)[i]);
}
// 8 consecutive elements -> bf16x8 (handles f32 or bf16 storage)
__device__ __forceinline__ u16x8 ld8(const void* p, size_t off, int isf) {
    u16x8 o;
    if (isf) {
        const float* f = (const float*)p + off;
        #pragma unroll
        for (int j = 0; j < 8; j++) o[j] = f2b(f[j]);
    } else {
        o = *(const u16x8*)((const bf16_t*)p + off);
    }
    return o;
}

__device__ __forceinline__ void stg16(const bf16_t* g, bf16_t* l) {
#ifdef HAS_GLL
    __builtin_amdgcn_global_load_lds(
        (const __attribute__((address_space(1))) unsigned int*)g,
        (__attribute__((address_space(3))) unsigned int*)l,
        16, 0, 0);
#else
    *(uint4*)l = *(const uint4*)g;
#endif
}

// wave-level bf16-vs-fp32 storage detection (lane i inspects word i of x).
__device__ __forceinline__ int detect_isf(const void* xraw) {
    const unsigned int* w = (const unsigned int*)xraw;
    unsigned int u = w[threadIdx.x & 63];
    float a = fabsf(__uint_as_float(u << 16));
    int g = (a >= 0.0009765625f && a <= 16.0f) ? 1 : 0;
    unsigned long long m = __ballot(g);
    return (__builtin_popcountll(m) >= 32) ? 0 : 1;
}

// ---- params block offsets (floats) ----
#define OFF_S0T0 0
#define OFF_W1   16
#define OFF_S1   592
#define OFF_H1   656
#define OFF_S2   720
#define OFF_H2   784
#define OFF_S3   848
#define OFF_H3   912
#define OFF_S4   976
#define OFF_H4   1040
#define OFF_SC5  1104
#define OFF_H5   1112
#define OFF_SC6  1624
#define OFF_H6   1632
#define OFF_SC7  2144
#define OFF_H7   2152
#define OFF_W8   2280
#define OFF_B8   3304
#define OFF_FLAG 4032

// ---------------------------------------------------------------------------
// ONE setup kernel, segmented:
//  [0,512)   w5 per-row 64x128 -> 128x64 LDS transpose (coalesced R+W)
//  [512,576) w3 per-oc transpose -> pixel-major
//  [576,640) w4 per-oc transpose -> pixel-major
//  [640,768) w6 copy (u16x8)
//  [768,800) w7 copy (u16x8)
//  [800,944) w2 permute (tiny, gather ok - src L2-resident)
//  944       BN-param fold
//  [945, 945+Bf/4)  conv1 for the FULL batch (one-pass mode only), with
//    bn0/bn1 folded locally -> runs concurrently with the transposes.
// ---------------------------------------------------------------------------
__global__ __launch_bounds__(256) void setup_fold_kernel(
    const void* __restrict__ x,
    const void* __restrict__ w2, const void* __restrict__ w3,
    const void* __restrict__ w4, const void* __restrict__ w5,
    const void* __restrict__ w6, const void* __restrict__ w7,
    bf16_t* __restrict__ w2p, bf16_t* __restrict__ w3p,
    bf16_t* __restrict__ w4p, bf16_t* __restrict__ w5p,
    bf16_t* __restrict__ w6b, bf16_t* __restrict__ w7b,
    const void* __restrict__ bn0p, const void* __restrict__ w1,
    const void* __restrict__ b1, const void* __restrict__ bn1p,
    const void* __restrict__ b2c, const void* __restrict__ bn2p,
    const void* __restrict__ bn3p, const void* __restrict__ bn4p,
    const void* __restrict__ b5, const void* __restrict__ bn5p,
    const void* __restrict__ b6, const void* __restrict__ bn6p,
    const void* __restrict__ b7, const void* __restrict__ bn7p,
    const void* __restrict__ w8, const void* __restrict__ b8,
    float* __restrict__ prm, bf16_t* __restrict__ c1, int Bf)
{
    const int t  = threadIdx.x;
    const int bb = blockIdx.x;
    const int isf = detect_isf(x);

    if (bb >= 945) {
        // ---- conv1 segment: transpose+bn0 -> conv1+bn1+relu, 4 samples ----
        const int b0 = (bb - 945) * 4;
        __shared__ float xn[720];
        __shared__ float w1s[576];

        float s0, t0;
        {
            float g = ldf(bn0p, 0, isf), be = ldf(bn0p, 1, isf);
            float m = ldf(bn0p, 2, isf), v = ldf(bn0p, 3, isf);
            s0 = g * rsqrtf(v + 1e-5f); t0 = be - m * s0;
        }
        for (int i = t; i < 576; i += 256) w1s[i] = ldf(w1, i, isf);
        for (int i = t; i < 720; i += 256) {
            int s = i / 180, r = i - s * 180;
            int row = r / 18, col = r - row * 18;
            float v = 0.f;
            if (row >= 1 && row <= 8 && col >= 1 && col <= 16)
                v = s0 * ldf(x, (b0 + s) * 128 + (col - 1) * 8 + (row - 1), isf) + t0;
            xn[i] = v;
        }

        const int oc0 = (t & 7) * 8;
        const int pg  = t >> 3;

        float s1[8], h1[8];
        #pragma unroll
        for (int j = 0; j < 8; j++) {
            const int ch = oc0 + j;
            float g = ldf(bn1p, ch, isf), be = ldf(bn1p, 64 + ch, isf);
            float m = ldf(bn1p, 128 + ch, isf), v = ldf(bn1p, 192 + ch, isf);
            s1[j] = g * rsqrtf(v + 1e-5f);
            h1[j] = s1[j] * ldf(b1, ch, isf) + (be - m * s1[j]);
        }
        __syncthreads();

        for (int s = 0; s < 4; s++) {
            const int b = b0 + s;
            const float* xs = xn + s * 180;
            #pragma unroll
            for (int m = 0; m < 4; m++) {
                int p = pg + 32 * m;
                int h = p >> 4, w = p & 15;
                float r[9];
                #pragma unroll
                for (int dh = 0; dh < 3; dh++)
                    #pragma unroll
                    for (int dw = 0; dw < 3; dw++)
                        r[dh * 3 + dw] = xs[(h + dh) * 18 + (w + dw)];
                u16x8 o;
                #pragma unroll
                for (int j = 0; j < 8; j++) {
                    float acc = 0.f;
                    #pragma unroll
                    for (int k = 0; k < 9; k++) acc += r[k] * w1s[(oc0 + j) * 9 + k];
                    o[j] = f2b(fmaxf(s1[j] * acc + h1[j], 0.f));
                }
                *(u16x8*)(c1 + (size_t)p * Bf * 64 + (size_t)b * 64 + oc0) = o;
            }
        }
        return;
    }

    if (bb < 512) {
        // w5 row nr: w5p[nr][p*64+c] = w5[nr][c*128+p]
        __shared__ unsigned short ls[128 * 66];
        const int nr = bb;
        const size_t so = (size_t)nr * 8192;
        #pragma unroll
        for (int k = 0; k < 4; k++) {
            const int e0 = (t + k * 256) * 8;      // e = c*128 + p (8 consec p)
            u16x8 v = ld8(w5, so + e0, isf);
            const int c = e0 >> 7, p0 = e0 & 127;
            #pragma unroll
            for (int j = 0; j < 8; j++) ls[(p0 + j) * 66 + c] = v[j];
        }
        __syncthreads();
        #pragma unroll
        for (int k = 0; k < 4; k++) {
            const int d0 = (t + k * 256) * 8;      // d = p*64 + c
            const int p = d0 >> 6, c0 = d0 & 63;
            u16x8 o;
            #pragma unroll
            for (int j = 0; j < 8; j++) o[j] = ls[p * 66 + c0 + j];
            *(u16x8*)(w5p + so + d0) = o;
        }
        return;
    }
    if (bb < 640) {
        // w3/w4 oc: dst[p*4096 + oc*64 + ic] = src[oc*8192 + ic*128 + p]
        __shared__ unsigned short ls[128 * 66];
        const int oc = (bb - 512) & 63;
        const void* src = (bb < 576) ? w3 : w4;
        bf16_t*    dst = (bb < 576) ? w3p : w4p;
        const size_t so = (size_t)oc * 8192;
        #pragma unroll
        for (int k = 0; k < 4; k++) {
            const int e0 = (t + k * 256) * 8;      // e = ic*128 + p
            u16x8 v = ld8(src, so + e0, isf);
            const int ic = e0 >> 7, p0 = e0 & 127;
            #pragma unroll
            for (int j = 0; j < 8; j++) ls[(p0 + j) * 66 + ic] = v[j];
        }
        __syncthreads();
        #pragma unroll
        for (int k = 0; k < 4; k++) {
            const int d0 = (t + k * 256) * 8;      // d = p*64 + ic
            const int p = d0 >> 6, ic0 = d0 & 63;
            u16x8 o;
            #pragma unroll
            for (int j = 0; j < 8; j++) o[j] = ls[p * 66 + ic0 + j];
            *(u16x8*)(dst + (size_t)p * 4096 + oc * 64 + ic0) = o;
        }
        return;
    }
    if (bb < 768) {      // w6: 262144 elems, 8/thread
        const int i0 = ((bb - 640) * 256 + t) * 8;
        *(u16x8*)(w6b + i0) = ld8(w6, i0, isf);
        return;
    }
    if (bb < 800) {      // w7: 65536 elems
        const int i0 = ((bb - 768) * 256 + t) * 8;
        *(u16x8*)(w7b + i0) = ld8(w7, i0, isf);
        return;
    }
    if (bb < 944) {      // w2 permute: 36864 elems (src tiny -> L2 gather ok)
        const int i = (bb - 800) * 256 + t;
        int oc = i / 576, r = i - oc * 576;
        int tap = r >> 6, ic = r & 63;
        w2p[i] = f2b(ldf(w2, oc * 576 + ic * 9 + tap, isf));
        return;
    }

    // ---- fold block (bb == 944) ----
    if (t == 0) prm[OFF_FLAG] = isf ? 1.0f : 0.0f;

    if (t == 0) {
        float g = ldf(bn0p, 0, isf), be = ldf(bn0p, 1, isf);
        float m = ldf(bn0p, 2, isf), v = ldf(bn0p, 3, isf);
        float s = g * rsqrtf(v + 1e-5f);
        prm[OFF_S0T0] = s; prm[OFF_S0T0 + 1] = be - m * s;
    }
    for (int i = t; i < 576; i += 256) prm[OFF_W1 + i] = ldf(w1, i, isf);

    if (t < 64) {
        {
            float g = ldf(bn1p, t, isf), be = ldf(bn1p, 64 + t, isf);
            float m = ldf(bn1p, 128 + t, isf), v = ldf(bn1p, 192 + t, isf);
            float s = g * rsqrtf(v + 1e-5f);
            prm[OFF_S1 + t] = s;
            prm[OFF_H1 + t] = s * ldf(b1, t, isf) + (be - m * s);
        }
        {
            float g = ldf(bn2p, t, isf), be = ldf(bn2p, 64 + t, isf);
            float m = ldf(bn2p, 128 + t, isf), v = ldf(bn2p, 192 + t, isf);
            float s = g * rsqrtf(v + 1e-5f);
            prm[OFF_S2 + t] = s;
            prm[OFF_H2 + t] = s * ldf(b2c, t, isf) + (be - m * s);
        }
        {
            float g = ldf(bn3p, t, isf), be = ldf(bn3p, 64 + t, isf);
            float m = ldf(bn3p, 128 + t, isf), v = ldf(bn3p, 192 + t, isf);
            float s = g * rsqrtf(v + 1e-5f);
            prm[OFF_S3 + t] = s;
            prm[OFF_H3 + t] = be - m * s;
        }
        {
            float g = ldf(bn4p, t, isf), be = ldf(bn4p, 64 + t, isf);
            float m = ldf(bn4p, 128 + t, isf), v = ldf(bn4p, 192 + t, isf);
            float s = g * rsqrtf(v + 1e-5f);
            prm[OFF_S4 + t] = s;
            prm[OFF_H4 + t] = be - m * s;
        }
    }
    {
        float g = ldf(bn5p, 0, isf), be = ldf(bn5p, 1, isf);
        float m = ldf(bn5p, 2, isf), v = ldf(bn5p, 3, isf);
        float s = g * rsqrtf(v + 1e-5f);
        if (t == 0) prm[OFF_SC5] = s;
        for (int i = t; i < 512; i += 256)
            prm[OFF_H5 + i] = s * ldf(b5, i, isf) + (be - m * s);
    }
    {
        float g = ldf(bn6p, 0, isf), be = ldf(bn6p, 1, isf);
        float m = ldf(bn6p, 2, isf), v = ldf(bn6p, 3, isf);
        float s = g * rsqrtf(v + 1e-5f);
        if (t == 0) prm[OFF_SC6] = s;
        for (int i = t; i < 512; i += 256)
            prm[OFF_H6 + i] = s * ldf(b6, i, isf) + (be - m * s);
    }
    {
        float g = ldf(bn7p, 0, isf), be = ldf(bn7p, 1, isf);
        float m = ldf(bn7p, 2, isf), v = ldf(bn7p, 3, isf);
        float s = g * rsqrtf(v + 1e-5f);
        if (t == 0) prm[OFF_SC7] = s;
        if (t < 128) prm[OFF_H7 + t] = s * ldf(b7, t, isf) + (be - m * s);
    }
    for (int i = t; i < 1024; i += 256) prm[OFF_W8 + i] = ldf(w8, i, isf);
    if (t < 8) prm[OFF_B8 + t] = ldf(b8, t, isf);
}

// ---------------------------------------------------------------------------
// conv1 standalone (FALLBACK chunked path only).
// ---------------------------------------------------------------------------
__global__ __launch_bounds__(256) void conv1_kernel(
    const void* __restrict__ x, const float* __restrict__ prm,
    bf16_t* __restrict__ c1, int Bc, int c0)
{
    __shared__ float xn[720];
    __shared__ float w1s[576];

    const int t = threadIdx.x;
    const int b0 = blockIdx.x * 4;
    const int isf = prm[OFF_FLAG] > 0.5f;
    const float s0 = prm[OFF_S0T0], t0 = prm[OFF_S0T0 + 1];

    for (int i = t; i < 576; i += 256) w1s[i] = prm[OFF_W1 + i];
    for (int i = t; i < 720; i += 256) {
        int s = i / 180, r = i - s * 180;
        int row = r / 18, col = r - row * 18;
        float v = 0.f;
        if (row >= 1 && row <= 8 && col >= 1 && col <= 16)
            v = s0 * ldf(x, (c0 + b0 + s) * 128 + (col - 1) * 8 + (row - 1), isf) + t0;
        xn[i] = v;
    }

    const int oc0 = (t & 7) * 8;
    const int pg  = t >> 3;

    float s1[8], h1[8];
    #pragma unroll
    for (int j = 0; j < 8; j++) {
        s1[j] = prm[OFF_S1 + oc0 + j];
        h1[j] = prm[OFF_H1 + oc0 + j];
    }
    __syncthreads();

    for (int s = 0; s < 4; s++) {
        const int b = b0 + s;
        const float* xs = xn + s * 180;
        #pragma unroll
        for (int m = 0; m < 4; m++) {
            int p = pg + 32 * m;
            int h = p >> 4, w = p & 15;
            float r[9];
            #pragma unroll
            for (int dh = 0; dh < 3; dh++)
                #pragma unroll
                for (int dw = 0; dw < 3; dw++)
                    r[dh * 3 + dw] = xs[(h + dh) * 18 + (w + dw)];
            u16x8 o;
            #pragma unroll
            for (int j = 0; j < 8; j++) {
                float acc = 0.f;
                #pragma unroll
                for (int k = 0; k < 9; k++) acc += r[k] * w1s[(oc0 + j) * 9 + k];
                o[j] = f2b(fmaxf(s1[j] * acc + h1[j], 0.f));
            }
            *(u16x8*)(c1 + (size_t)p * Bc * 64 + (size_t)b * 64 + oc0) = o;
        }
    }
}

// ---------------------------------------------------------------------------
// Fused MFMA: conv2(im2col K=576) + bn2relu -> lc3(K=64) + bn3relu
//             -> lc4(K=64) + bn4relu.  Grid (Bc/256, 128 pixels).
//
// conv2 now uses a 4-DEEP staging ring + counted vmcnt + raw s_barrier (T4):
// the old 2-phase loop forced vmcnt(0) drains at all 18 barriers (48% total
// pipe-busy).  Ring schedule per step s: wait vmcnt(5) [stage(s+1)'s loads,
// issued a FULL iteration earlier, stay in flight; everything older -- incl.
// stage(s) -- has landed], s_barrier, issue stage(s+2), compute(s).
// Slot s&3 is rewritten >=2 barriers after its last reader -> race-free.
// LDS 80 KiB (act 4x16K + wt 4x4K) -> 2 blocks/CU; in-block pipeline depth
// replaces the lost cross-block TLP.  smC/lc-wt alias the ring after a full
// __syncthreads.  XCD swizzle unchanged.
// ---------------------------------------------------------------------------
__global__ __launch_bounds__(256) void fused_mfma_kernel(
    const bf16_t* __restrict__ c1, const bf16_t* __restrict__ w2p,
    const bf16_t* __restrict__ w3p, const bf16_t* __restrict__ w4p,
    const float* __restrict__ prm, bf16_t* __restrict__ bufA, int Bc)
{
    __shared__ bf16_t sm[40960];       // 80 KiB: act ring 4x8192 + wt ring 4x2048
    const int t    = threadIdx.x;
    const int lane = t & 63;
    const int wv   = t >> 6;

    int btile, p;
    {
        const int nbx = gridDim.x;
        const int id = blockIdx.x + nbx * blockIdx.y;
        if ((nbx & 7) == 0) {
            const int xcd = id & 7;
            const int k   = id >> 3;
            p     = k & 127;
            btile = xcd + 8 * (k >> 7);       // one btile per XCD at a time
        } else {
            btile = blockIdx.x; p = blockIdx.y;
        }
    }
    const int m0 = btile * 256;
    const int h  = p >> 4, w = p & 15;

    const int fr = lane & 15;
    const int fg = lane >> 4;
    const int swz4 = (fr >> 1) & 3;

    // hoisted staging coords
    const int gS    = (t & 3) ^ ((t >> 3) & 3);
    const int rA    = t >> 2;
    const int coff0 = rA * 64 + gS * 8;
    const int w2off = rA * 576 + gS * 8;

    // lc3/lc4 weights -> registers now; consumed via ds_write much later
    u16x8 wr3[2], wr4[2];
    {
        const bf16_t* w3b = w3p + (size_t)p * 4096 + coff0;
        const bf16_t* w4b = w4p + (size_t)p * 4096 + coff0;
        wr3[0] = *(const u16x8*)(w3b);
        wr3[1] = *(const u16x8*)(w3b + 32);
        wr4[0] = *(const u16x8*)(w4b);
        wr4[1] = *(const u16x8*)(w4b + 32);
    }

    // acc[i][j]: i = oc tile (M), j = batch tile (N) within wave's 64-row band
    f32x4 acc[4][4];
    #pragma unroll
    for (int i = 0; i < 4; i++)
        #pragma unroll
        for (int j = 0; j < 4; j++)
            acc[i][j] = (f32x4){0.f, 0.f, 0.f, 0.f};

    const bf16_t* c1b = c1 + (size_t)m0 * 64 + coff0;
    const size_t planeStride = (size_t)Bc * 64;

// step-k tap validity (k literal after unroll; h,w block-uniform runtime)
#define PV(k) (h + ((k) >> 1) / 3 - 1 >= 0 && h + ((k) >> 1) / 3 - 1 < 8 && \
               w + ((k) >> 1) % 3 - 1 >= 0 && w + ((k) >> 1) % 3 - 1 < 16)
// stage step k into ring slot k&3 (5 gll: 4 act + 1 wt)
#define STAGE(k) do {                                                         \
    const int tap_ = (k) >> 1, icq_ = ((k) & 1) * 32;                         \
    const int hh_ = h + tap_ / 3 - 1, ww_ = w + tap_ % 3 - 1;                 \
    const int nb_ = (k) & 3;                                                  \
    const bf16_t* ab_ = c1b + (size_t)(hh_ * 16 + ww_) * planeStride + icq_;  \
    _Pragma("unroll")                                                         \
    for (int u_ = 0; u_ < 4; u_++)                                            \
        stg16(ab_ + u_ * 4096, sm + nb_ * 8192 + t * 8 + u_ * 2048);          \
    stg16(w2p + w2off + tap_ * 64 + icq_, sm + 32768 + nb_ * 2048 + t * 8);   \
} while (0)

    // ---------------- conv2: 4-deep ring, counted vmcnt, 18 k-steps --------
    if (PV(0)) STAGE(0);
    if (PV(1)) STAGE(1);

    #pragma unroll
    for (int s = 0; s < 18; s++) {
        // pre-barrier: everything older than stage(s+1)'s 5 loads must land
        if (s < 17 && PV(s + 1))
            asm volatile("s_waitcnt vmcnt(5)" ::: "memory");
        else
            asm volatile("s_waitcnt vmcnt(0)" ::: "memory");
        __builtin_amdgcn_sched_barrier(0);
        __builtin_amdgcn_s_barrier();
        __builtin_amdgcn_sched_barrier(0);
        if (s + 2 < 18 && PV(s + 2)) STAGE(s + 2);
        if (PV(s)) {
            const bf16_t* Ab = sm + (s & 3) * 8192;            // activations
            const bf16_t* Bb = sm + 32768 + (s & 3) * 2048;    // weights
            bf16x8 hf[4], wf[4];
            #pragma unroll
            for (int j = 0; j < 4; j++)
                hf[j] = *(const bf16x8*)(Ab + ((wv * 64 + j * 16 + fr) * 4 + (fg ^ swz4)) * 8);
            #pragma unroll
            for (int i = 0; i < 4; i++)
                wf[i] = *(const bf16x8*)(Bb + ((i * 16 + fr) * 4 + (fg ^ swz4)) * 8);
            #pragma unroll
            for (int i = 0; i < 4; i++)
                #pragma unroll
                for (int j = 0; j < 4; j++)
                    acc[i][j] = __builtin_amdgcn_mfma_f32_16x16x32_bf16(
                        wf[i], hf[j], acc[i][j], 0, 0, 0);
        }
    }
#undef STAGE
#undef PV
    __syncthreads();   // full drain; ring region is reused as smC below

    // epilogue macro: D(m=oc contiguous 4, n=b) -> smC[b][oc], packed b64 writes
#define EPILOGUE(SOFF, HOFF)                                                  \
    _Pragma("unroll")                                                         \
    for (int i = 0; i < 4; i++) {                                             \
        const int oc0e = i * 16 + fg * 4;                                     \
        const float4 sv = *(const float4*)(prm + (SOFF) + oc0e);              \
        const float4 hv = *(const float4*)(prm + (HOFF) + oc0e);              \
        _Pragma("unroll")                                                     \
        for (int j = 0; j < 4; j++) {                                         \
            const int bi = wv * 64 + j * 16 + fr;                             \
            float v0 = fmaxf(sv.x * acc[i][j][0] + hv.x, 0.f);                \
            float v1 = fmaxf(sv.y * acc[i][j][1] + hv.y, 0.f);                \
            float v2 = fmaxf(sv.z * acc[i][j][2] + hv.z, 0.f);                \
            float v3 = fmaxf(sv.w * acc[i][j][3] + hv.w, 0.f);                \
            uint2 pk; pk.x = pk2(v0, v1); pk.y = pk2(v2, v3);                 \
            *(uint2*)(sm + bi * 72 + oc0e) = pk;                              \
        }                                                                     \
    }

    // conv2 epilogue -> smC [b][oc] stride 72 (own band) + stage lc3 ks0 wts
    EPILOGUE(OFF_S2, OFF_H2)
    *(u16x8*)(sm + 18432 + t * 8) = wr3[0];
    __syncthreads();

    // ---------------- lc3: K=64 (weights from registers) ----------------
    #pragma unroll
    for (int i = 0; i < 4; i++)
        #pragma unroll
        for (int j = 0; j < 4; j++)
            acc[i][j] = (f32x4){0.f, 0.f, 0.f, 0.f};

    #pragma unroll
    for (int ks = 0; ks < 2; ks++) {
        if (ks == 1) {
            __syncthreads();                       // all ks0 weight reads done
            *(u16x8*)(sm + 18432 + t * 8) = wr3[1];
            __syncthreads();
        }
        bf16x8 hf[4], wf[4];
        #pragma unroll
        for (int j = 0; j < 4; j++)
            hf[j] = *(const bf16x8*)(sm + (wv * 64 + j * 16 + fr) * 72 + ks * 32 + fg * 8);
        #pragma unroll
        for (int i = 0; i < 4; i++)
            wf[i] = *(const bf16x8*)(sm + 18432 + ((i * 16 + fr) * 4 + (fg ^ swz4)) * 8);
        #pragma unroll
        for (int i = 0; i < 4; i++)
            #pragma unroll
            for (int j = 0; j < 4; j++)
                acc[i][j] = __builtin_amdgcn_mfma_f32_16x16x32_bf16(
                    wf[i], hf[j], acc[i][j], 0, 0, 0);
    }

    // lc3 epilogue (own band; own-band reads already consumed)
    EPILOGUE(OFF_S3, OFF_H3)
    __syncthreads();                               // lc3 ks1 weight reads done
    *(u16x8*)(sm + 18432 + t * 8) = wr4[0];
    __syncthreads();

    // ---------------- lc4: K=64 ----------------
    #pragma unroll
    for (int i = 0; i < 4; i++)
        #pragma unroll
        for (int j = 0; j < 4; j++)
            acc[i][j] = (f32x4){0.f, 0.f, 0.f, 0.f};

    #pragma unroll
    for (int ks = 0; ks < 2; ks++) {
        if (ks == 1) {
            __syncthreads();
            *(u16x8*)(sm + 18432 + t * 8) = wr4[1];
            __syncthreads();
        }
        bf16x8 hf[4], wf[4];
        #pragma unroll
        for (int j = 0; j < 4; j++)
            hf[j] = *(const bf16x8*)(sm + (wv * 64 + j * 16 + fr) * 72 + ks * 32 + fg * 8);
        #pragma unroll
        for (int i = 0; i < 4; i++)
            wf[i] = *(const bf16x8*)(sm + 18432 + ((i * 16 + fr) * 4 + (fg ^ swz4)) * 8);
        #pragma unroll
        for (int i = 0; i < 4; i++)
            #pragma unroll
            for (int j = 0; j < 4; j++)
                acc[i][j] = __builtin_amdgcn_mfma_f32_16x16x32_bf16(
                    wf[i], hf[j], acc[i][j], 0, 0, 0);
    }

    // lc4 epilogue -> smC, then barrier, then coalesced bufA write (all bands)
    EPILOGUE(OFF_S4, OFF_H4)
#undef EPILOGUE
    __syncthreads();

    const int orow = t >> 3, wc0 = (t & 7) * 8;
    #pragma unroll
    for (int pass = 0; pass < 8; pass++) {
        const int row = orow + pass * 32;
        *(uint4*)(bufA + (size_t)(m0 + row) * 8192 + p * 64 + wc0) =
            *(const uint4*)(sm + row * 72 + wc0);
    }
}

// ---------------------------------------------------------------------------
// MFMA GEMM: out[M][N] = relu(s*(A.W^T)+shift), bf16.
// BM=128, BN=64, BK=64.  4 waves 2x2, wave tile 64x32, 16 MFMA per barrier.
// (~80 us fc5 = 860-870 TF, m97-plateau for this shape; m131 says counted
// vmcnt is neutral on this structure at >=2 blocks/CU -- left untouched.)
// XCD swizzle groups an A-panel's N-blocks time-adjacent on one XCD.
// ---------------------------------------------------------------------------
__global__ __launch_bounds__(256) void gemm_mfma(
    const bf16_t* __restrict__ A, const bf16_t* __restrict__ W,
    const float* __restrict__ prm, int sc_off, int sh_off,
    bf16_t* __restrict__ out, int K, int N)
{
    __shared__ bf16_t sm[24576];
    const int t    = threadIdx.x;
    const int lane = t & 63;
    const int wv   = t >> 6;
    const int wr   = wv >> 1, wc = wv & 1;

    int bm, bn;
    {
        const int nx = gridDim.x, ny = gridDim.y;
        const int id = blockIdx.x + nx * blockIdx.y;
        if ((nx & 7) == 0) {
            const int xcd = id & 7;
            const int k   = id >> 3;
            const int pl  = k / ny;       // panel group within this XCD
            bn = k - pl * ny;
            bm = xcd + 8 * pl;
        } else {
            bm = blockIdx.x; bn = blockIdx.y;
        }
    }
    const int m0 = bm * 128, n0 = bn * 64;

    const int fr = lane & 15;
    const int fg = lane >> 4;
    const int swz8 = fr & 7;

    const bf16_t* srcA[4]; bf16_t* dstA[4];
    #pragma unroll
    for (int u = 0; u < 4; u++) {
        const int c = t + 256 * u;
        const int row = c >> 3;
        const int g = (c & 7) ^ (row & 7);
        srcA[u] = A + (size_t)(m0 + row) * K + g * 8;
        dstA[u] = sm + c * 8;
    }
    const bf16_t* srcB[2]; bf16_t* dstB[2];
    #pragma unroll
    for (int u = 0; u < 2; u++) {
        const int c = t + 256 * u;
        const int row = c >> 3;
        const int g = (c & 7) ^ (row & 7);
        srcB[u] = W + (size_t)(n0 + row) * K + g * 8;
        dstB[u] = sm + 16384 + c * 8;
    }

    f32x4 acc[4][2];
    #pragma unroll
    for (int i = 0; i < 4; i++)
        #pragma unroll
        for (int j = 0; j < 2; j++)
            acc[i][j] = (f32x4){0.f, 0.f, 0.f, 0.f};

    const int KS = K >> 6;

    #pragma unroll
    for (int u = 0; u < 4; u++) stg16(srcA[u], dstA[u]);
    #pragma unroll
    for (int u = 0; u < 2; u++) stg16(srcB[u], dstB[u]);

    for (int ks = 0; ks < KS; ks++) {
        const int cur = ks & 1;
        __syncthreads();
        if (ks + 1 < KS) {
            const int nb = cur ^ 1;
            const int kk = (ks + 1) << 6;
            #pragma unroll
            for (int u = 0; u < 4; u++) stg16(srcA[u] + kk, dstA[u] + nb * 8192);
            #pragma unroll
            for (int u = 0; u < 2; u++) stg16(srcB[u] + kk, dstB[u] + nb * 4096);
        }
        const bf16_t* Ab = sm + cur * 8192;
        const bf16_t* Bb = sm + 16384 + cur * 4096;
        bf16x8 af[4][2], bf2[2][2];
        #pragma unroll
        for (int i = 0; i < 4; i++)
            #pragma unroll
            for (int hh = 0; hh < 2; hh++) {
                const int r = wr * 64 + i * 16 + fr;
                const int g = hh * 4 + fg;
                af[i][hh] = *(const bf16x8*)(Ab + (r * 8 + (g ^ swz8)) * 8);
            }
        #pragma unroll
        for (int j = 0; j < 2; j++)
            #pragma unroll
            for (int hh = 0; hh < 2; hh++) {
                const int r = wc * 32 + j * 16 + fr;
                const int g = hh * 4 + fg;
                bf2[j][hh] = *(const bf16x8*)(Bb + (r * 8 + (g ^ swz8)) * 8);
            }
        #pragma unroll
        for (int hh = 0; hh < 2; hh++)
            #pragma unroll
            for (int i = 0; i < 4; i++)
                #pragma unroll
                for (int j = 0; j < 2; j++)
                    acc[i][j] = __builtin_amdgcn_mfma_f32_16x16x32_bf16(
                        af[i][hh], bf2[j][hh], acc[i][j], 0, 0, 0);
    }

    const float s    = prm[sc_off];
    const int   orow = fg * 4;
    const int   ocol = fr;
    #pragma unroll
    for (int j = 0; j < 2; j++) {
        const int n  = n0 + wc * 32 + j * 16 + ocol;
        const float sh = prm[sh_off + n];
        #pragma unroll
        for (int i = 0; i < 4; i++) {
            const int mb = m0 + wr * 64 + i * 16 + orow;
            #pragma unroll
            for (int r = 0; r < 4; r++) {
                float v = fmaxf(s * acc[i][j][r] + sh, 0.f);
                out[(size_t)(mb + r) * N + n] = f2b(v);
            }
        }
    }
}

// ---------------------------------------------------------------------------
// fc78: fused fc7 (N=128, K=512, bn7+relu) -> fc8 (128->8) per 128-row block.
// ---------------------------------------------------------------------------
__global__ __launch_bounds__(256) void fc78_kernel(
    const bf16_t* __restrict__ A, const bf16_t* __restrict__ W,
    const float* __restrict__ prm, void* __restrict__ out, int c0)
{
    __shared__ bf16_t sm[32768];       // 64 KB: k-loop staging; then smC+w8s
    const int t    = threadIdx.x;
    const int lane = t & 63;
    const int wv   = t >> 6;
    const int wr   = wv >> 1, wc = wv & 1;
    const int m0   = blockIdx.x * 128;
    const int K    = 512;

    const int fr = lane & 15;
    const int fg = lane >> 4;
    const int swz8 = fr & 7;

    const bf16_t* srcA[4]; bf16_t* dstA[4];
    #pragma unroll
    for (int u = 0; u < 4; u++) {
        const int c = t + 256 * u;
        const int row = c >> 3;
        const int g = (c & 7) ^ (row & 7);
        srcA[u] = A + (size_t)(m0 + row) * K + g * 8;
        dstA[u] = sm + c * 8;
    }
    const bf16_t* srcB[4]; bf16_t* dstB[4];
    #pragma unroll
    for (int u = 0; u < 4; u++) {
        const int c = t + 256 * u;
        const int row = c >> 3;
        const int g = (c & 7) ^ (row & 7);
        srcB[u] = W + (size_t)row * K + g * 8;
        dstB[u] = sm + 16384 + c * 8;
    }

    f32x4 acc[4][4];
    #pragma unroll
    for (int i = 0; i < 4; i++)
        #pragma unroll
        for (int j = 0; j < 4; j++)
            acc[i][j] = (f32x4){0.f, 0.f, 0.f, 0.f};

    const int KS = 8;

    #pragma unroll
    for (int u = 0; u < 4; u++) stg16(srcA[u], dstA[u]);
    #pragma unroll
    for (int u = 0; u < 4; u++) stg16(srcB[u], dstB[u]);

    for (int ks = 0; ks < KS; ks++) {
        const int cur = ks & 1;
        __syncthreads();
        if (ks + 1 < KS) {
            const int nb = cur ^ 1;
            const int kk = (ks + 1) << 6;
            #pragma unroll
            for (int u = 0; u < 4; u++) stg16(srcA[u] + kk, dstA[u] + nb * 8192);
            #pragma unroll
            for (int u = 0; u < 4; u++) stg16(srcB[u] + kk, dstB[u] + nb * 8192);
        }
        const bf16_t* Ab = sm + cur * 8192;
        const bf16_t* Bb = sm + 16384 + cur * 8192;
        bf16x8 af[4][2], bf2[4][2];
        #pragma unroll
        for (int i = 0; i < 4; i++)
            #pragma unroll
            for (int hh = 0; hh < 2; hh++) {
                const int r = wr * 64 + i * 16 + fr;
                const int g = hh * 4 + fg;
                af[i][hh] = *(const bf16x8*)(Ab + (r * 8 + (g ^ swz8)) * 8);
            }
        #pragma unroll
        for (int j = 0; j < 4; j++)
            #pragma unroll
            for (int hh = 0; hh < 2; hh++) {
                const int r = wc * 64 + j * 16 + fr;
                const int g = hh * 4 + fg;
                bf2[j][hh] = *(const bf16x8*)(Bb + (r * 8 + (g ^ swz8)) * 8);
            }
        #pragma unroll
        for (int hh = 0; hh < 2; hh++)
            #pragma unroll
            for (int i = 0; i < 4; i++)
                #pragma unroll
                for (int j = 0; j < 4; j++)
                    acc[i][j] = __builtin_amdgcn_mfma_f32_16x16x32_bf16(
                        af[i][hh], bf2[j][hh], acc[i][j], 0, 0, 0);
    }

    // all k-loop LDS reads done -> reuse sm: smC [128][130] bf16 + w8s f32
    __syncthreads();
    float* w8s = (float*)(sm + 16640);            // bytes 33280..37375
    for (int i = t; i < 1024; i += 256) w8s[i] = prm[OFF_W8 + i];

    const float s = prm[OFF_SC7];
    #pragma unroll
    for (int j = 0; j < 4; j++) {
        const int n  = wc * 64 + j * 16 + fr;
        const float sh = prm[OFF_H7 + n];
        #pragma unroll
        for (int i = 0; i < 4; i++) {
            const int row0 = wr * 64 + i * 16 + fg * 4;
            #pragma unroll
            for (int r = 0; r < 4; r++) {
                float v = fmaxf(s * acc[i][j][r] + sh, 0.f);
                sm[(row0 + r) * 130 + n] = f2b(v);
            }
        }
    }
    __syncthreads();

    // fc8: thread t -> row r = t&127, n-half = t>>7 (4 outputs)
    const int isf = prm[OFF_FLAG] > 0.5f;
    const int r   = t & 127;
    const int n4  = (t >> 7) * 4;
    float a4[4];
    #pragma unroll
    for (int q = 0; q < 4; q++) a4[q] = prm[OFF_B8 + n4 + q];
    for (int k = 0; k < 128; k++) {
        const float hv = b2f(sm[r * 130 + k]);
        #pragma unroll
        for (int q = 0; q < 4; q++) a4[q] += hv * w8s[(n4 + q) * 128 + k];
    }
    const size_t ob = (size_t)(c0 + m0 + r) * 8 + n4;
    if (isf) {
        float4 o4 = make_float4(a4[0], a4[1], a4[2], a4[3]);
        *(float4*)((float*)out + ob) = o4;
    } else {
        uint2 pk; pk.x = pk2(a4[0], a4[1]); pk.y = pk2(a4[2], a4[3]);
        *(uint2*)((bf16_t*)out + ob) = pk;
    }
}

// ---------------------------------------------------------------------------
extern "C" void kernel_launch(void* const* d_in, const int* in_sizes, int n_in,
                              void* d_out, int out_size, void* d_ws, size_t ws_size,
                              hipStream_t stream)
{
    const void* x    = d_in[0];
    const void* bn0p = d_in[1];
    const void* w1   = d_in[2];
    const void* b1   = d_in[3];
    const void* bn1p = d_in[4];
    const void* w2   = d_in[5];
    const void* b2c  = d_in[6];
    const void* bn2p = d_in[7];
    const void* w3   = d_in[8];
    const void* bn3p = d_in[9];
    const void* w4   = d_in[10];
    const void* bn4p = d_in[11];
    const void* w5   = d_in[12];
    const void* b5   = d_in[13];
    const void* bn5p = d_in[14];
    const void* w6   = d_in[15];
    const void* b6   = d_in[16];
    const void* bn6p = d_in[17];
    const void* w7   = d_in[18];
    const void* b7   = d_in[19];
    const void* bn7p = d_in[20];
    const void* w8   = d_in[21];
    const void* b8   = d_in[22];

    char* base = (char*)d_ws;
    float*  prm = (float*)(base + 0);            //    16384 B
    bf16_t* w2p = (bf16_t*)(base + 16384);       //    73728 B
    bf16_t* w3p = (bf16_t*)(base + 90112);       //  1048576 B
    bf16_t* w4p = (bf16_t*)(base + 1138688);     //  1048576 B
    bf16_t* w5p = (bf16_t*)(base + 2187264);     //  8388608 B
    bf16_t* w6b = (bf16_t*)(base + 10575872);    //   524288 B
    bf16_t* w7b = (bf16_t*)(base + 11100160);    //   131072 B
    char*   acts = base + 11231232;

    const int B = 8192;
    const size_t FIXED = 11231232ull;

    // one-pass if c1 fits for the whole batch, else 2-chunk, else tight loop
    const size_t NEED_1PASS = FIXED + (size_t)B * 16384ull + (size_t)B * 18688ull;
    const size_t NEED_2PASS = FIXED + 4096ull * 16384ull + (size_t)B * 18688ull;

    if (ws_size >= NEED_2PASS) {
        const int Bf = (ws_size >= NEED_1PASS) ? 8192 : 4096;

        bf16_t* c1   = (bf16_t*)acts;                    // [128][Bf][64]
        bf16_t* bufA = c1 + (size_t)Bf * 8192;           // [B][8192]
        bf16_t* bufC = bufA + (size_t)B * 8192;          // [B][512]
        bf16_t* bufD = bufC + (size_t)B * 512;           // [B][512]

        // conv1 runs inside setup (overlapped) when one-pass
        const int extra = (Bf == 8192) ? Bf / 4 : 0;
        setup_fold_kernel<<<945 + extra, 256, 0, stream>>>(
            x, w2, w3, w4, w5, w6, w7, w2p, w3p, w4p, w5p, w6b, w7b,
            bn0p, w1, b1, bn1p, b2c, bn2p, bn3p, bn4p,
            b5, bn5p, b6, bn6p, b7, bn7p, w8, b8, prm, c1, Bf);

        for (int c0 = 0; c0 < B; c0 += Bf) {
            if (extra == 0)
                conv1_kernel<<<Bf / 4, 256, 0, stream>>>(x, prm, c1, Bf, c0);
            fused_mfma_kernel<<<dim3(Bf / 256, 128), 256, 0, stream>>>(
                c1, w2p, w3p, w4p, prm, bufA + (size_t)c0 * 8192, Bf);
        }
        gemm_mfma<<<dim3(B / 128, 8), 256, 0, stream>>>(
            bufA, w5p, prm, OFF_SC5, OFF_H5, bufC, 8192, 512);
        gemm_mfma<<<dim3(B / 128, 8), 256, 0, stream>>>(
            bufC, w6b, prm, OFF_SC6, OFF_H6, bufD, 512, 512);
        fc78_kernel<<<B / 128, 256, 0, stream>>>(bufD, w7b, prm, d_out, 0);
    } else {
        size_t avail = (ws_size > FIXED) ? (ws_size - FIXED) : 0;
        int Bc = 8192;
        while (Bc > 256 && (size_t)Bc * 35072ull > avail) Bc >>= 1;

        bf16_t* c1   = (bf16_t*)acts;
        bf16_t* bufA = c1 + (size_t)Bc * 8192;
        bf16_t* bufC = bufA + (size_t)Bc * 8192;
        bf16_t* bufD = bufC + (size_t)Bc * 512;

        setup_fold_kernel<<<945, 256, 0, stream>>>(
            x, w2, w3, w4, w5, w6, w7, w2p, w3p, w4p, w5p, w6b, w7b,
            bn0p, w1, b1, bn1p, b2c, bn2p, bn3p, bn4p,
            b5, bn5p, b6, bn6p, b7, bn7p, w8, b8, prm, c1, Bc);

        for (int c0 = 0; c0 < B; c0 += Bc) {
            conv1_kernel<<<Bc / 4, 256, 0, stream>>>(x, prm, c1, Bc, c0);
            fused_mfma_kernel<<<dim3(Bc / 256, 128), 256, 0, stream>>>(
                c1, w2p, w3p, w4p, prm, bufA, Bc);
            gemm_mfma<<<dim3(Bc / 128, 8), 256, 0, stream>>>(
                bufA, w5p, prm, OFF_SC5, OFF_H5, bufC, 8192, 512);
            gemm_mfma<<<dim3(Bc / 128, 8), 256, 0, stream>>>(
                bufC, w6b, prm, OFF_SC6, OFF_H6, bufD, 512, 512);
            fc78_kernel<<<Bc / 128, 256, 0, stream>>>(bufD, w7b, prm, d_out, c0);
        }
    }
}